// Round 1
// baseline (1242.610 us; speedup 1.0000x reference)
//
#include <hip/hip_runtime.h>
#include <math.h>

#define N_NODES 100000
#define N_EDGES 1600000
#define F_IN    256
#define NHEAD   8
#define NDIM    8
#define NC      16
#define NEG     0.2f

// ---------- order-preserving float <-> u32 encoding for atomic max ----------
__device__ __forceinline__ unsigned encf(float f) {
    unsigned u = __float_as_uint(f);
    return (u & 0x80000000u) ? ~u : (u | 0x80000000u);
}
__device__ __forceinline__ float decf(unsigned u) {
    return __uint_as_float((u & 0x80000000u) ? (u & 0x7FFFFFFFu) : ~u);
}
__device__ __forceinline__ float lrelu(float x) { return x > 0.f ? x : NEG * x; }

// ---------- K1: h = x@W1 [N,64]; s,t = einsum(h, a_src/a_dst) [N,8] ----------
__global__ __launch_bounds__(256) void gemm1_kernel(
    const float* __restrict__ x, const float* __restrict__ W1,
    const float* __restrict__ a_src, const float* __restrict__ a_dst,
    float* __restrict__ h, float* __restrict__ s, float* __restrict__ t) {
    __shared__ float Wl[F_IN * 64];  // 64 KB
    int tid = threadIdx.x;
    const float4* W4 = (const float4*)W1;
    float4* Wl4 = (float4*)Wl;
#pragma unroll
    for (int i = 0; i < 16; ++i) Wl4[tid + 256 * i] = W4[tid + 256 * i];
    __syncthreads();
    int j = tid & 63;          // output column = head*8+d
    int n = blockIdx.x * 4 + (tid >> 6);
    const float4* xr = (const float4*)(x + (size_t)n * F_IN);
    float acc = 0.f;
#pragma unroll 8
    for (int k4 = 0; k4 < F_IN / 4; ++k4) {
        float4 xv = xr[k4];
        acc += xv.x * Wl[(k4 * 4 + 0) * 64 + j];
        acc += xv.y * Wl[(k4 * 4 + 1) * 64 + j];
        acc += xv.z * Wl[(k4 * 4 + 2) * 64 + j];
        acc += xv.w * Wl[(k4 * 4 + 3) * 64 + j];
    }
    h[(size_t)n * 64 + j] = acc;
    float vs = acc * a_src[j];
    float vt = acc * a_dst[j];
#pragma unroll
    for (int o = 1; o < 8; o <<= 1) {
        vs += __shfl_xor(vs, o, 64);
        vt += __shfl_xor(vt, o, 64);
    }
    if ((j & 7) == 0) {
        int head = j >> 3;
        s[n * NHEAD + head] = vs;
        t[n * NHEAD + head] = vt;
    }
}

// ---------- K2: segment max over dst (layer 1), per (edge, head) ----------
__global__ __launch_bounds__(256) void edge_max1(
    const int* __restrict__ esrc, const int* __restrict__ edst,
    const float* __restrict__ s, const float* __restrict__ t,
    unsigned* __restrict__ menc) {
    int g = blockIdx.x * 256 + threadIdx.x;
    if (g >= N_EDGES * NHEAD) return;
    int e = g >> 3, hh = g & 7;
    int src = esrc[e], dst = edst[e];
    float ev = lrelu(s[src * NHEAD + hh] + t[dst * NHEAD + hh]);
    atomicMax(menc + dst * NHEAD + hh, encf(ev));
}

// ---------- K3: denom = segment_sum(exp(e-m)) (layer 1) ----------
__global__ __launch_bounds__(256) void edge_den1(
    const int* __restrict__ esrc, const int* __restrict__ edst,
    const float* __restrict__ s, const float* __restrict__ t,
    const unsigned* __restrict__ menc, float* __restrict__ den) {
    int g = blockIdx.x * 256 + threadIdx.x;
    if (g >= N_EDGES * NHEAD) return;
    int e = g >> 3, hh = g & 7;
    int src = esrc[e], dst = edst[e];
    float ev = lrelu(s[src * NHEAD + hh] + t[dst * NHEAD + hh]);
    float ex = expf(ev - decf(menc[dst * NHEAD + hh]));
    atomicAdd(den + dst * NHEAD + hh, ex);
}

// ---------- K4: acc1[dst] += ex * h[src]  (unnormalized; 64 lanes/edge) ----------
__global__ __launch_bounds__(256) void edge_sc1(
    const int* __restrict__ esrc, const int* __restrict__ edst,
    const float* __restrict__ s, const float* __restrict__ t,
    const unsigned* __restrict__ menc, const float* __restrict__ h,
    float* __restrict__ acc1) {
    int tid = threadIdx.x;
    int e = blockIdx.x * 4 + (tid >> 6);
    int j = tid & 63, hh = j >> 3;
    int src = esrc[e], dst = edst[e];
    float ev = lrelu(s[src * NHEAD + hh] + t[dst * NHEAD + hh]);
    float ex = expf(ev - decf(menc[dst * NHEAD + hh]));
    float v = ex * h[(size_t)src * 64 + j];
    atomicAdd(acc1 + (size_t)dst * 64 + j, v);
}

// ---------- K6: h1 = elu(acc1/den1); h2 = h1@W2; s2,t2 ----------
__global__ __launch_bounds__(256) void gemm2_kernel(
    const float* __restrict__ acc1, const float* __restrict__ den1,
    const float* __restrict__ W2, const float* __restrict__ a2s,
    const float* __restrict__ a2d,
    float* __restrict__ h2, float* __restrict__ s2, float* __restrict__ t2) {
    __shared__ float Wl[64 * NC];      // 4 KB
    __shared__ float h1l[16 * 64];     // 4 KB : 16 rows of h1
    int tid = threadIdx.x;
    ((float4*)Wl)[tid] = ((const float4*)W2)[tid];
    // compute 4 h1 values per thread (contiguous float4 of acc1)
    {
        float4 raw = ((const float4*)acc1)[(size_t)blockIdx.x * 256 + tid];
        int f = tid * 4;               // flat index in [16 rows][64 cols]
        int rr = f >> 6, kk = f & 63;
        int nn = blockIdx.x * 16 + rr;
        float dn = den1[nn * NHEAD + (kk >> 3)] + 1e-16f;
        float v0 = raw.x / dn, v1 = raw.y / dn, v2 = raw.z / dn, v3 = raw.w / dn;
        h1l[f + 0] = v0 > 0.f ? v0 : (expf(v0) - 1.f);
        h1l[f + 1] = v1 > 0.f ? v1 : (expf(v1) - 1.f);
        h1l[f + 2] = v2 > 0.f ? v2 : (expf(v2) - 1.f);
        h1l[f + 3] = v3 > 0.f ? v3 : (expf(v3) - 1.f);
    }
    __syncthreads();
    int c = tid & 15, r = tid >> 4;
    int n = blockIdx.x * 16 + r;
    float a = 0.f;
#pragma unroll 8
    for (int k = 0; k < 64; ++k) a += h1l[r * 64 + k] * Wl[k * NC + c];
    h2[(size_t)n * NC + c] = a;
    float vs = a * a2s[c];
    float vt = a * a2d[c];
#pragma unroll
    for (int o = 1; o < 16; o <<= 1) {
        vs += __shfl_xor(vs, o, 64);
        vt += __shfl_xor(vt, o, 64);
    }
    if (c == 0) { s2[n] = vs; t2[n] = vt; }
}

// ---------- K7: segment max (layer 2), per edge ----------
__global__ __launch_bounds__(256) void edge_max2(
    const int* __restrict__ esrc, const int* __restrict__ edst,
    const float* __restrict__ s2, const float* __restrict__ t2,
    unsigned* __restrict__ menc2) {
    int e = blockIdx.x * 256 + threadIdx.x;
    if (e >= N_EDGES) return;
    float ev = lrelu(s2[esrc[e]] + t2[edst[e]]);
    atomicMax(menc2 + edst[e], encf(ev));
}

// ---------- K8: denom (layer 2) ----------
__global__ __launch_bounds__(256) void edge_den2(
    const int* __restrict__ esrc, const int* __restrict__ edst,
    const float* __restrict__ s2, const float* __restrict__ t2,
    const unsigned* __restrict__ menc2, float* __restrict__ den2) {
    int e = blockIdx.x * 256 + threadIdx.x;
    if (e >= N_EDGES) return;
    int dst = edst[e];
    float ev = lrelu(s2[esrc[e]] + t2[dst]);
    atomicAdd(den2 + dst, expf(ev - decf(menc2[dst])));
}

// ---------- K9: acc2[dst] += ex * h2[src]  (16 lanes/edge) ----------
__global__ __launch_bounds__(256) void edge_sc2(
    const int* __restrict__ esrc, const int* __restrict__ edst,
    const float* __restrict__ s2, const float* __restrict__ t2,
    const unsigned* __restrict__ menc2, const float* __restrict__ h2,
    float* __restrict__ acc2) {
    int tid = threadIdx.x;
    int e = blockIdx.x * 16 + (tid >> 4);
    int c = tid & 15;
    int src = esrc[e], dst = edst[e];
    float ev = lrelu(s2[src] + t2[dst]);
    float ex = expf(ev - decf(menc2[dst]));
    atomicAdd(acc2 + (size_t)dst * NC + c, ex * h2[(size_t)src * NC + c]);
}

// ---------- K10: logits = acc2/den2; log_softmax ----------
__global__ __launch_bounds__(256) void logsm_kernel(
    const float* __restrict__ acc2, const float* __restrict__ den2,
    float* __restrict__ out) {
    int n = blockIdx.x * 256 + threadIdx.x;
    if (n >= N_NODES) return;
    float dn = den2[n] + 1e-16f;
    float v[NC];
    const float4* a4 = (const float4*)(acc2 + (size_t)n * NC);
#pragma unroll
    for (int i = 0; i < 4; ++i) {
        float4 r = a4[i];
        v[i * 4 + 0] = r.x / dn; v[i * 4 + 1] = r.y / dn;
        v[i * 4 + 2] = r.z / dn; v[i * 4 + 3] = r.w / dn;
    }
    float mx = v[0];
#pragma unroll
    for (int i = 1; i < NC; ++i) mx = fmaxf(mx, v[i]);
    float sum = 0.f;
#pragma unroll
    for (int i = 0; i < NC; ++i) sum += expf(v[i] - mx);
    float lse = mx + logf(sum);
    float4* o4 = (float4*)(out + (size_t)n * NC);
#pragma unroll
    for (int i = 0; i < 4; ++i) {
        float4 r;
        r.x = v[i * 4 + 0] - lse; r.y = v[i * 4 + 1] - lse;
        r.z = v[i * 4 + 2] - lse; r.w = v[i * 4 + 3] - lse;
        o4[i] = r;
    }
}

extern "C" void kernel_launch(void* const* d_in, const int* in_sizes, int n_in,
                              void* d_out, int out_size, void* d_ws, size_t ws_size,
                              hipStream_t stream) {
    const float* x     = (const float*)d_in[0];
    const int*   eidx  = (const int*)d_in[1];   // [2, E] int32
    const float* W1    = (const float*)d_in[2];
    const float* a1s   = (const float*)d_in[3];
    const float* a1d   = (const float*)d_in[4];
    const float* W2    = (const float*)d_in[5];
    const float* a2s   = (const float*)d_in[6];
    const float* a2d   = (const float*)d_in[7];
    float* out = (float*)d_out;
    const int* esrc = eidx;
    const int* edst = eidx + N_EDGES;

    // ---- workspace layout (floats/u32, all 16B-aligned) ----
    // zeroed region first (one memset):
    //   menc1 [N*8] u32 | den1 [N*8] | acc1 [N*64] | menc2 [N] u32 | den2 [N] | acc2 [N*16]
    // then (written before read):
    //   h [N*64] | s [N*8] | t [N*8] | h2 [N*16] | s2 [N] | t2 [N]
    char* p = (char*)d_ws;
    unsigned* menc1 = (unsigned*)p;                 p += (size_t)N_NODES * NHEAD * 4;
    float*    den1  = (float*)p;                    p += (size_t)N_NODES * NHEAD * 4;
    float*    acc1  = (float*)p;                    p += (size_t)N_NODES * 64 * 4;
    unsigned* menc2 = (unsigned*)p;                 p += (size_t)N_NODES * 4;
    float*    den2  = (float*)p;                    p += (size_t)N_NODES * 4;
    float*    acc2  = (float*)p;                    p += (size_t)N_NODES * NC * 4;
    size_t zero_bytes = (size_t)(p - (char*)d_ws);
    float*    h     = (float*)p;                    p += (size_t)N_NODES * 64 * 4;
    float*    s     = (float*)p;                    p += (size_t)N_NODES * NHEAD * 4;
    float*    t     = (float*)p;                    p += (size_t)N_NODES * NHEAD * 4;
    float*    h2    = (float*)p;                    p += (size_t)N_NODES * NC * 4;
    float*    s2    = (float*)p;                    p += (size_t)N_NODES * 4;
    float*    t2    = (float*)p;                    p += (size_t)N_NODES * 4;

    hipMemsetAsync(d_ws, 0, zero_bytes, stream);

    gemm1_kernel<<<N_NODES / 4, 256, 0, stream>>>(x, W1, a1s, a1d, h, s, t);
    edge_max1<<<(N_EDGES * NHEAD) / 256, 256, 0, stream>>>(esrc, edst, s, t, menc1);
    edge_den1<<<(N_EDGES * NHEAD) / 256, 256, 0, stream>>>(esrc, edst, s, t, menc1, den1);
    edge_sc1<<<N_EDGES / 4, 256, 0, stream>>>(esrc, edst, s, t, menc1, h, acc1);
    gemm2_kernel<<<N_NODES / 16, 256, 0, stream>>>(acc1, den1, W2, a2s, a2d, h2, s2, t2);
    edge_max2<<<(N_EDGES + 255) / 256, 256, 0, stream>>>(esrc, edst, s2, t2, menc2);
    edge_den2<<<(N_EDGES + 255) / 256, 256, 0, stream>>>(esrc, edst, s2, t2, menc2, den2);
    edge_sc2<<<N_EDGES / 16, 256, 0, stream>>>(esrc, edst, s2, t2, menc2, h2, acc2);
    logsm_kernel<<<(N_NODES + 255) / 256, 256, 0, stream>>>(acc2, den2, out);
}

// Round 2
// 945.681 us; speedup vs baseline: 1.3140x; 1.3140x over previous
//
#include <hip/hip_runtime.h>
#include <math.h>

#define N_NODES 100000
#define N_EDGES 1600000
#define F_IN    256
#define NHEAD   8
#define NC      16
#define NEG     0.2f

__device__ __forceinline__ float lrelu(float x) { return x > 0.f ? x : NEG * x; }

// ---------- K0: Wt4[k4][c] = {W[4k4+0][c], W[4k4+1][c], W[4k4+2][c], W[4k4+3][c]} ----------
__global__ __launch_bounds__(256) void wtrans_kernel(const float* __restrict__ W1,
                                                     float4* __restrict__ Wt4) {
    int t = blockIdx.x * 256 + threadIdx.x;   // 4096 total
    int k4 = t >> 6, c = t & 63;
    float4 v;
    v.x = W1[(k4 * 4 + 0) * 64 + c];
    v.y = W1[(k4 * 4 + 1) * 64 + c];
    v.z = W1[(k4 * 4 + 2) * 64 + c];
    v.w = W1[(k4 * 4 + 3) * 64 + c];
    Wt4[t] = v;
}

// ---------- K1: h = x@W1 [N,64]; s,t fused. Register-blocked f32 GEMM. ----------
// Block: 128 rows x 64 cols, 4 waves (each wave: 32 rows x 64 cols).
// Lane (lr=lane&7, lc=lane>>3): rows w*32+lr*4+i (i<4), cols lc+8*j (j<8).
__global__ __launch_bounds__(256, 3) void gemm1_kernel(
    const float* __restrict__ x, const float4* __restrict__ Wt4,
    const float* __restrict__ a_src, const float* __restrict__ a_dst,
    float* __restrict__ h, float* __restrict__ s, float* __restrict__ t) {
    __shared__ float4 xs[128 * 16];   // [row][k4 ^ ((row>>3)&7)]  32 KB
    __shared__ float4 Ws[16 * 64];    // [k4][c]                   16 KB
    int tid = threadIdx.x;
    int w = tid >> 6, lane = tid & 63;
    int lr = lane & 7, lc = lane >> 3;
    int n0 = blockIdx.x * 128;

    float acc[4][8];
#pragma unroll
    for (int i = 0; i < 4; ++i)
#pragma unroll
        for (int j = 0; j < 8; ++j) acc[i][j] = 0.f;

    int ri[4], sw[4];
#pragma unroll
    for (int i = 0; i < 4; ++i) { ri[i] = w * 32 + lr * 4 + i; sw[i] = (ri[i] >> 3) & 7; }

    for (int kt = 0; kt < 4; ++kt) {
        // stage x tile: 128 rows x 16 float4, coalesced reads, swizzled LDS writes
#pragma unroll
        for (int pp = 0; pp < 8; ++pp) {
            int row = pp * 16 + (tid >> 4);
            int kl = tid & 15;
            int gr = n0 + row; if (gr >= N_NODES) gr = 0;
            float4 v = *(const float4*)(x + (size_t)gr * 256 + kt * 64 + kl * 4);
            xs[row * 16 + (kl ^ ((row >> 3) & 7))] = v;
        }
        // stage W tile: 16 k4 x 64 cols, straight contiguous copy
#pragma unroll
        for (int i = 0; i < 4; ++i) Ws[tid + i * 256] = Wt4[kt * 1024 + tid + i * 256];
        __syncthreads();
#pragma unroll
        for (int k4 = 0; k4 < 16; ++k4) {
            float4 wv[8];
#pragma unroll
            for (int j = 0; j < 8; ++j) wv[j] = Ws[k4 * 64 + lc + 8 * j];
#pragma unroll
            for (int i = 0; i < 4; ++i) {
                float4 xv = xs[ri[i] * 16 + (k4 ^ sw[i])];
#pragma unroll
                for (int j = 0; j < 8; ++j) {
                    acc[i][j] += xv.x * wv[j].x;
                    acc[i][j] += xv.y * wv[j].y;
                    acc[i][j] += xv.z * wv[j].z;
                    acc[i][j] += xv.w * wv[j].w;
                }
            }
        }
        __syncthreads();
    }

    // epilogue: write h; fused s,t (per-head reductions across lc lanes)
    float as_[8], ad_[8];
#pragma unroll
    for (int j = 0; j < 8; ++j) { int c = lc + 8 * j; as_[j] = a_src[c]; ad_[j] = a_dst[c]; }
#pragma unroll
    for (int i = 0; i < 4; ++i) {
        int gr = n0 + ri[i];
        float ps[8], pt[8];
#pragma unroll
        for (int j = 0; j < 8; ++j) {
            ps[j] = acc[i][j] * as_[j];
            pt[j] = acc[i][j] * ad_[j];
            ps[j] += __shfl_xor(ps[j], 8, 64);
            ps[j] += __shfl_xor(ps[j], 16, 64);
            ps[j] += __shfl_xor(ps[j], 32, 64);
            pt[j] += __shfl_xor(pt[j], 8, 64);
            pt[j] += __shfl_xor(pt[j], 16, 64);
            pt[j] += __shfl_xor(pt[j], 32, 64);
        }
        if (gr < N_NODES) {
#pragma unroll
            for (int j = 0; j < 8; ++j) h[(size_t)gr * 64 + lc + 8 * j] = acc[i][j];
            if (lc == 0) {
#pragma unroll
                for (int j = 0; j < 8; ++j) { s[gr * 8 + j] = ps[j]; t[gr * 8 + j] = pt[j]; }
            }
        }
    }
}

// ---------- K2: fused layer-1 edge pass: acc1[dst] += ex*h[src], den1[dst] += ex ----------
__global__ __launch_bounds__(256) void edge_sc1(
    const int* __restrict__ esrc, const int* __restrict__ edst,
    const float* __restrict__ s, const float* __restrict__ t,
    const float* __restrict__ h, float* __restrict__ acc1, float* __restrict__ den1) {
    int tid = threadIdx.x;
    int e = blockIdx.x * 4 + (tid >> 6);
    int j = tid & 63, hh = j >> 3;
    int src = esrc[e], dst = edst[e];
    float ev = lrelu(s[src * 8 + hh] + t[dst * 8 + hh]);
    float ex = __expf(ev);
    atomicAdd(acc1 + (size_t)dst * 64 + j, ex * h[(size_t)src * 64 + j]);
    if ((j & 7) == 0) atomicAdd(den1 + dst * 8 + hh, ex);
}

// ---------- K3: h1 = elu(acc1/den1); h2 = h1@W2; s2,t2 ----------
__global__ __launch_bounds__(256) void gemm2_kernel(
    const float* __restrict__ acc1, const float* __restrict__ den1,
    const float* __restrict__ W2, const float* __restrict__ a2s,
    const float* __restrict__ a2d,
    float* __restrict__ h2, float* __restrict__ s2, float* __restrict__ t2) {
    __shared__ float Wl[64 * NC];      // 4 KB
    __shared__ float h1l[16 * 64];     // 4 KB
    int tid = threadIdx.x;
    ((float4*)Wl)[tid] = ((const float4*)W2)[tid];
    {
        float4 raw = ((const float4*)acc1)[(size_t)blockIdx.x * 256 + tid];
        int f = tid * 4;
        int rr = f >> 6, kk = f & 63;
        int nn = blockIdx.x * 16 + rr;
        float dn = den1[nn * NHEAD + (kk >> 3)] + 1e-16f;
        float v0 = raw.x / dn, v1 = raw.y / dn, v2 = raw.z / dn, v3 = raw.w / dn;
        h1l[f + 0] = v0 > 0.f ? v0 : (__expf(v0) - 1.f);
        h1l[f + 1] = v1 > 0.f ? v1 : (__expf(v1) - 1.f);
        h1l[f + 2] = v2 > 0.f ? v2 : (__expf(v2) - 1.f);
        h1l[f + 3] = v3 > 0.f ? v3 : (__expf(v3) - 1.f);
    }
    __syncthreads();
    int c = tid & 15, r = tid >> 4;
    int n = blockIdx.x * 16 + r;
    float a = 0.f;
#pragma unroll 16
    for (int k = 0; k < 64; ++k) a += h1l[r * 64 + k] * Wl[k * NC + c];
    h2[(size_t)n * NC + c] = a;
    float vs = a * a2s[c];
    float vt = a * a2d[c];
#pragma unroll
    for (int o = 1; o < 16; o <<= 1) {
        vs += __shfl_xor(vs, o, 64);
        vt += __shfl_xor(vt, o, 64);
    }
    if (c == 0) { s2[n] = vs; t2[n] = vt; }
}

// ---------- K4: fused layer-2 edge pass ----------
__global__ __launch_bounds__(256) void edge_sc2(
    const int* __restrict__ esrc, const int* __restrict__ edst,
    const float* __restrict__ s2, const float* __restrict__ t2,
    const float* __restrict__ h2, float* __restrict__ acc2, float* __restrict__ den2) {
    int tid = threadIdx.x;
    int e = blockIdx.x * 16 + (tid >> 4);
    int c = tid & 15;
    int src = esrc[e], dst = edst[e];
    float ev = lrelu(s2[src] + t2[dst]);
    float ex = __expf(ev);
    atomicAdd(acc2 + (size_t)dst * NC + c, ex * h2[(size_t)src * NC + c]);
    if (c == 0) atomicAdd(den2 + dst, ex);
}

// ---------- K5: logits = acc2/den2; log_softmax ----------
__global__ __launch_bounds__(256) void logsm_kernel(
    const float* __restrict__ acc2, const float* __restrict__ den2,
    float* __restrict__ out) {
    int n = blockIdx.x * 256 + threadIdx.x;
    if (n >= N_NODES) return;
    float dn = den2[n] + 1e-16f;
    float v[NC];
    const float4* a4 = (const float4*)(acc2 + (size_t)n * NC);
#pragma unroll
    for (int i = 0; i < 4; ++i) {
        float4 r = a4[i];
        v[i * 4 + 0] = r.x / dn; v[i * 4 + 1] = r.y / dn;
        v[i * 4 + 2] = r.z / dn; v[i * 4 + 3] = r.w / dn;
    }
    float mx = v[0];
#pragma unroll
    for (int i = 1; i < NC; ++i) mx = fmaxf(mx, v[i]);
    float sum = 0.f;
#pragma unroll
    for (int i = 0; i < NC; ++i) sum += __expf(v[i] - mx);
    float lse = mx + __logf(sum);
    float4* o4 = (float4*)(out + (size_t)n * NC);
#pragma unroll
    for (int i = 0; i < 4; ++i) {
        float4 r;
        r.x = v[i * 4 + 0] - lse; r.y = v[i * 4 + 1] - lse;
        r.z = v[i * 4 + 2] - lse; r.w = v[i * 4 + 3] - lse;
        o4[i] = r;
    }
}

extern "C" void kernel_launch(void* const* d_in, const int* in_sizes, int n_in,
                              void* d_out, int out_size, void* d_ws, size_t ws_size,
                              hipStream_t stream) {
    const float* x   = (const float*)d_in[0];
    const int*   eidx = (const int*)d_in[1];   // [2, E] int32
    const float* W1  = (const float*)d_in[2];
    const float* a1s = (const float*)d_in[3];
    const float* a1d = (const float*)d_in[4];
    const float* W2  = (const float*)d_in[5];
    const float* a2s = (const float*)d_in[6];
    const float* a2d = (const float*)d_in[7];
    float* out = (float*)d_out;
    const int* esrc = eidx;
    const int* edst = eidx + N_EDGES;

    // ---- workspace layout ----
    // zeroed region: den1 [N*8] | acc1 [N*64] | den2 [N] | acc2 [N*16]
    // then: Wt4 [4096 float4] | h [N*64] | s [N*8] | t [N*8] | h2 [N*16] | s2 [N] | t2 [N]
    char* p = (char*)d_ws;
    float*  den1 = (float*)p;   p += (size_t)N_NODES * NHEAD * 4;
    float*  acc1 = (float*)p;   p += (size_t)N_NODES * 64 * 4;
    float*  den2 = (float*)p;   p += (size_t)N_NODES * 4;
    float*  acc2 = (float*)p;   p += (size_t)N_NODES * NC * 4;
    size_t zero_bytes = (size_t)(p - (char*)d_ws);
    float4* Wt4  = (float4*)p;  p += (size_t)4096 * 16;
    float*  h    = (float*)p;   p += (size_t)N_NODES * 64 * 4;
    float*  s    = (float*)p;   p += (size_t)N_NODES * NHEAD * 4;
    float*  t    = (float*)p;   p += (size_t)N_NODES * NHEAD * 4;
    float*  h2   = (float*)p;   p += (size_t)N_NODES * NC * 4;
    float*  s2   = (float*)p;   p += (size_t)N_NODES * 4;
    float*  t2   = (float*)p;   p += (size_t)N_NODES * 4;

    hipMemsetAsync(d_ws, 0, zero_bytes, stream);

    wtrans_kernel<<<16, 256, 0, stream>>>(W1, Wt4);
    gemm1_kernel<<<(N_NODES + 127) / 128, 256, 0, stream>>>(x, Wt4, a1s, a1d, h, s, t);
    edge_sc1<<<N_EDGES / 4, 256, 0, stream>>>(esrc, edst, s, t, h, acc1, den1);
    gemm2_kernel<<<N_NODES / 16, 256, 0, stream>>>(acc1, den1, W2, a2s, a2d, h2, s2, t2);
    edge_sc2<<<N_EDGES / 16, 256, 0, stream>>>(esrc, edst, s2, t2, h2, acc2, den2);
    logsm_kernel<<<(N_NODES + 255) / 256, 256, 0, stream>>>(acc2, den2, out);
}

// Round 3
// 641.792 us; speedup vs baseline: 1.9362x; 1.4735x over previous
//
#include <hip/hip_runtime.h>
#include <math.h>

#define N_NODES 100000
#define N_EDGES 1600000
#define NHEAD   8
#define NC      16
#define NEG     0.2f

typedef __attribute__((ext_vector_type(4))) float f32x4;
typedef __attribute__((ext_vector_type(8))) short s16x8;

__device__ __forceinline__ float lrelu(float x) { return x > 0.f ? x : NEG * x; }
__device__ __forceinline__ short bf16rne(float f) {
    unsigned u = __float_as_uint(f);
    return (short)((u + 0x7FFFu + ((u >> 16) & 1u)) >> 16);
}

// ---------- K0: pack W1 (256x64 f32) into bf16 fragment-major layout ----------
// unit u = (j*8+ks)*64 + lane holds 8 bf16: W1[ks*32+(lane>>4)*8+i][j*16+(lane&15)]
__global__ __launch_bounds__(256) void wtrans_kernel(const float* __restrict__ W1,
                                                     float4* __restrict__ Wt) {
    int u = blockIdx.x * 256 + threadIdx.x;   // 2048 units
    int j = u >> 9, ks = (u >> 6) & 7, l = u & 63;
    int colc = j * 16 + (l & 15);
    int k0 = ks * 32 + (l >> 4) * 8;
    union { s16x8 s; float4 f; } pk;
#pragma unroll
    for (int i = 0; i < 8; ++i) pk.s[i] = bf16rne(W1[(size_t)(k0 + i) * 64 + colc]);
    Wt[u] = pk.f;
}

// ---------- K1: h = x@W1 via bf16 MFMA. Block = 128 rows, 4 waves x 32 rows ----------
__global__ __launch_bounds__(256) void gemm1_kernel(
    const float* __restrict__ x, const float4* __restrict__ Wt,
    float* __restrict__ h) {
    __shared__ float4 WtL[2048];   // 32 KB, fragment-major (conflict-free reads)
    int tid = threadIdx.x;
#pragma unroll
    for (int i = 0; i < 8; ++i) WtL[tid + i * 256] = Wt[tid + i * 256];
    int w = tid >> 6, lane = tid & 63;
    int n0 = blockIdx.x * 128;
    int r0 = n0 + w * 32 + (lane & 15);
    int r1 = r0 + 16;
    int cr0 = r0 < N_NODES ? r0 : 0;
    int cr1 = r1 < N_NODES ? r1 : 0;
    int koff = (lane >> 4) * 8;
    f32x4 acc[2][4];
#pragma unroll
    for (int r = 0; r < 2; ++r)
#pragma unroll
        for (int j = 0; j < 4; ++j) acc[r][j] = (f32x4)0.f;
    __syncthreads();
#pragma unroll
    for (int ks = 0; ks < 8; ++ks) {
        const float* p0 = x + (size_t)cr0 * 256 + ks * 32 + koff;
        const float* p1 = x + (size_t)cr1 * 256 + ks * 32 + koff;
        float4 a0l = *(const float4*)p0, a0h = *(const float4*)(p0 + 4);
        float4 a1l = *(const float4*)p1, a1h = *(const float4*)(p1 + 4);
        s16x8 A0, A1;
        A0[0] = bf16rne(a0l.x); A0[1] = bf16rne(a0l.y); A0[2] = bf16rne(a0l.z); A0[3] = bf16rne(a0l.w);
        A0[4] = bf16rne(a0h.x); A0[5] = bf16rne(a0h.y); A0[6] = bf16rne(a0h.z); A0[7] = bf16rne(a0h.w);
        A1[0] = bf16rne(a1l.x); A1[1] = bf16rne(a1l.y); A1[2] = bf16rne(a1l.z); A1[3] = bf16rne(a1l.w);
        A1[4] = bf16rne(a1h.x); A1[5] = bf16rne(a1h.y); A1[6] = bf16rne(a1h.z); A1[7] = bf16rne(a1h.w);
#pragma unroll
        for (int j = 0; j < 4; ++j) {
            s16x8 B = *(s16x8*)&WtL[(j * 8 + ks) * 64 + lane];
            acc[0][j] = __builtin_amdgcn_mfma_f32_16x16x32_bf16(A0, B, acc[0][j], 0, 0, 0);
            acc[1][j] = __builtin_amdgcn_mfma_f32_16x16x32_bf16(A1, B, acc[1][j], 0, 0, 0);
        }
    }
    // epilogue: D layout col=lane&15, row=(lane>>4)*4+reg
    int rbase = (lane >> 4) * 4;
#pragma unroll
    for (int r = 0; r < 2; ++r) {
        int growb = n0 + w * 32 + r * 16 + rbase;
#pragma unroll
        for (int reg = 0; reg < 4; ++reg) {
            int grow = growb + reg;
            if (grow < N_NODES) {
                float* hp = h + (size_t)grow * 64 + (lane & 15);
#pragma unroll
                for (int j = 0; j < 4; ++j) hp[j * 16] = acc[r][j][reg];
            }
        }
    }
}

// ---------- K2: s,t logits from h ----------
__global__ __launch_bounds__(256) void st_kernel(const float* __restrict__ h,
    const float* __restrict__ a1s, const float* __restrict__ a1d,
    float* __restrict__ s, float* __restrict__ t) {
    int g = blockIdx.x * 256 + threadIdx.x;   // 800000 = node*8+head
    int hh = g & 7;
    const float4* hp = (const float4*)(h + (size_t)g * 8);
    float4 v0 = hp[0], v1 = hp[1];
    const float* as = a1s + hh * 8;
    const float* ad = a1d + hh * 8;
    float ps = v0.x * as[0] + v0.y * as[1] + v0.z * as[2] + v0.w * as[3]
             + v1.x * as[4] + v1.y * as[5] + v1.z * as[6] + v1.w * as[7];
    float pt = v0.x * ad[0] + v0.y * ad[1] + v0.z * ad[2] + v0.w * ad[3]
             + v1.x * ad[4] + v1.y * ad[5] + v1.z * ad[6] + v1.w * ad[7];
    s[g] = ps; t[g] = pt;
}

// ---------- K3: degree histogram ----------
__global__ __launch_bounds__(256) void hist_kernel(const int* __restrict__ edst,
                                                   int* __restrict__ count) {
    int e = blockIdx.x * 256 + threadIdx.x;
    if (e < N_EDGES) atomicAdd(&count[edst[e]], 1);
}

// ---------- K4: exclusive scan (single block, 1024 threads, 4 elems/thread) ----------
__global__ __launch_bounds__(1024) void scan_kernel(const int* __restrict__ count,
                                                    int* __restrict__ rowptr,
                                                    int* __restrict__ cursor) {
    __shared__ int wsum[16];
    __shared__ int wpre[16];
    int tid = threadIdx.x, wid = tid >> 6, lane = tid & 63;
    int running = 0;
    for (int base = 0; base < 25000; base += 1024) {
        int i4 = base + tid;
        int4 v = make_int4(0, 0, 0, 0);
        if (i4 < 25000) v = ((const int4*)count)[i4];
        int t0 = v.x, t1 = t0 + v.y, t2 = t1 + v.z, t3 = t2 + v.w;
        int inc = t3;
#pragma unroll
        for (int off = 1; off < 64; off <<= 1) {
            int nb = __shfl_up(inc, off, 64);
            if (lane >= off) inc += nb;
        }
        if (lane == 63) wsum[wid] = inc;
        __syncthreads();
        if (wid == 0) {
            int wv = (lane < 16) ? wsum[lane] : 0;
            int winc = wv;
#pragma unroll
            for (int off = 1; off < 16; off <<= 1) {
                int nb = __shfl_up(winc, off, 64);
                if (lane >= off) winc += nb;
            }
            if (lane < 16) wpre[lane] = winc - wv;
        }
        __syncthreads();
        int excl = inc - t3 + wpre[wid] + running;
        if (i4 < 25000) {
            int o = i4 * 4;
            rowptr[o] = excl;          cursor[o] = excl;
            rowptr[o + 1] = excl + t0; cursor[o + 1] = excl + t0;
            rowptr[o + 2] = excl + t1; cursor[o + 2] = excl + t1;
            rowptr[o + 3] = excl + t2; cursor[o + 3] = excl + t2;
        }
        running += wpre[15] + wsum[15];
        __syncthreads();
    }
    if (tid == 0) rowptr[N_NODES] = running;
}

// ---------- K5: scatter edges into CSR (col = src per slot) ----------
__global__ __launch_bounds__(256) void scatter_kernel(const int* __restrict__ esrc,
    const int* __restrict__ edst, int* __restrict__ cursor, int* __restrict__ col) {
    int e = blockIdx.x * 256 + threadIdx.x;
    if (e >= N_EDGES) return;
    int pos = atomicAdd(&cursor[edst[e]], 1);
    col[pos] = esrc[e];
}

// ---------- K6: layer-1 aggregation, one wave per dst; writes h1=elu(attn) ----------
__global__ __launch_bounds__(256) void agg1_kernel(
    const int* __restrict__ rowptr, const int* __restrict__ col,
    const float* __restrict__ s, const float* __restrict__ t,
    const float* __restrict__ h, float* __restrict__ h1) {
    int tid = threadIdx.x;
    int d = blockIdx.x * 4 + (tid >> 6);
    int lane = tid & 63, hh = lane >> 3;
    int beg = rowptr[d], end = rowptr[d + 1];
    float tv = t[d * 8 + hh];
    float acc = 0.f, den = 0.f;   // all 8 lanes of a head compute identical ex -> den needs no shuffle
    for (int p = beg; p < end; ++p) {
        int src = col[p];
        float ex = __expf(lrelu(s[src * 8 + hh] + tv));
        acc += ex * h[(size_t)src * 64 + lane];
        den += ex;
    }
    float v = acc / (den + 1e-16f);
    h1[(size_t)d * 64 + lane] = v > 0.f ? v : __expf(v) - 1.f;
}

// ---------- K7: h2 = h1@W2; s2,t2 fused ----------
__global__ __launch_bounds__(256) void gemm2_kernel(
    const float* __restrict__ h1, const float* __restrict__ W2,
    const float* __restrict__ a2s, const float* __restrict__ a2d,
    float* __restrict__ h2, float* __restrict__ s2, float* __restrict__ t2) {
    __shared__ float Wl[64 * NC];       // 4 KB
    __shared__ float h1l[16 * 65];      // padded stride 65: conflict-free
    int tid = threadIdx.x;
    ((float4*)Wl)[tid] = ((const float4*)W2)[tid];
    {
        float4 raw = ((const float4*)h1)[(size_t)blockIdx.x * 256 + tid];
        int f = tid * 4, rr = f >> 6, kk = f & 63;
        float* dp = &h1l[rr * 65 + kk];
        dp[0] = raw.x; dp[1] = raw.y; dp[2] = raw.z; dp[3] = raw.w;
    }
    __syncthreads();
    int c = tid & 15, r = tid >> 4;
    int n = blockIdx.x * 16 + r;
    float a = 0.f;
#pragma unroll 16
    for (int k = 0; k < 64; ++k) a += h1l[r * 65 + k] * Wl[k * NC + c];
    h2[(size_t)n * NC + c] = a;
    float vs = a * a2s[c];
    float vt = a * a2d[c];
#pragma unroll
    for (int o = 1; o < 16; o <<= 1) {
        vs += __shfl_xor(vs, o, 64);
        vt += __shfl_xor(vt, o, 64);
    }
    if (c == 0) { s2[n] = vs; t2[n] = vt; }
}

// ---------- K8: layer-2 aggregation + fused log_softmax, 16 lanes per dst ----------
__global__ __launch_bounds__(256) void agg2_kernel(
    const int* __restrict__ rowptr, const int* __restrict__ col,
    const float* __restrict__ s2, const float* __restrict__ t2,
    const float* __restrict__ h2, float* __restrict__ out) {
    int tid = threadIdx.x;
    int d = blockIdx.x * 16 + (tid >> 4);
    int c = tid & 15;
    int beg = rowptr[d], end = rowptr[d + 1];
    float tv = t2[d];
    float acc = 0.f, den = 0.f;
    for (int p = beg; p < end; ++p) {
        int src = col[p];
        float ex = __expf(lrelu(s2[src] + tv));
        acc += ex * h2[(size_t)src * 16 + c];
        den += ex;
    }
    float v = acc / (den + 1e-16f);
    float mx = v;
#pragma unroll
    for (int o = 1; o < 16; o <<= 1) mx = fmaxf(mx, __shfl_xor(mx, o, 64));
    float e = __expf(v - mx), sum = e;
#pragma unroll
    for (int o = 1; o < 16; o <<= 1) sum += __shfl_xor(sum, o, 64);
    out[(size_t)d * NC + c] = v - mx - __logf(sum);
}

extern "C" void kernel_launch(void* const* d_in, const int* in_sizes, int n_in,
                              void* d_out, int out_size, void* d_ws, size_t ws_size,
                              hipStream_t stream) {
    const float* x   = (const float*)d_in[0];
    const int*  eidx = (const int*)d_in[1];   // [2, E] int32
    const float* W1  = (const float*)d_in[2];
    const float* a1s = (const float*)d_in[3];
    const float* a1d = (const float*)d_in[4];
    const float* W2  = (const float*)d_in[5];
    const float* a2s = (const float*)d_in[6];
    const float* a2d = (const float*)d_in[7];
    float* out = (float*)d_out;
    const int* esrc = eidx;
    const int* edst = eidx + N_EDGES;

    // ---- workspace layout ----
    char* p = (char*)d_ws;
    int*    count  = (int*)p;    p += (size_t)N_NODES * 4;          // zeroed
    int*    cursor = (int*)p;    p += (size_t)N_NODES * 4;
    int*    rowptr = (int*)p;    p += (size_t)(N_NODES + 4) * 4;
    int*    col    = (int*)p;    p += (size_t)N_EDGES * 4;
    float4* Wt     = (float4*)p; p += (size_t)2048 * 16;
    float*  h      = (float*)p;  p += (size_t)N_NODES * 64 * 4;
    float*  s      = (float*)p;  p += (size_t)N_NODES * 8 * 4;
    float*  t      = (float*)p;  p += (size_t)N_NODES * 8 * 4;
    float*  h1     = (float*)p;  p += (size_t)N_NODES * 64 * 4;
    float*  h2     = (float*)p;  p += (size_t)N_NODES * NC * 4;
    float*  s2     = (float*)p;  p += (size_t)N_NODES * 4;
    float*  t2     = (float*)p;  p += (size_t)N_NODES * 4;

    hipMemsetAsync(count, 0, (size_t)N_NODES * 4, stream);

    wtrans_kernel<<<8, 256, 0, stream>>>(W1, Wt);
    hist_kernel<<<N_EDGES / 256, 256, 0, stream>>>(edst, count);
    gemm1_kernel<<<(N_NODES + 127) / 128, 256, 0, stream>>>(x, Wt, h);
    scan_kernel<<<1, 1024, 0, stream>>>(count, rowptr, cursor);
    st_kernel<<<(N_NODES * 8) / 256, 256, 0, stream>>>(h, a1s, a1d, s, t);
    scatter_kernel<<<N_EDGES / 256, 256, 0, stream>>>(esrc, edst, cursor, col);
    agg1_kernel<<<N_NODES / 4, 256, 0, stream>>>(rowptr, col, s, t, h, h1);
    gemm2_kernel<<<N_NODES / 16, 256, 0, stream>>>(h1, W2, a2s, a2d, h2, s2, t2);
    agg2_kernel<<<N_NODES / 16, 256, 0, stream>>>(rowptr, col, s2, t2, h2, out);
}

// Round 4
// 530.637 us; speedup vs baseline: 2.3417x; 1.2095x over previous
//
#include <hip/hip_runtime.h>
#include <math.h>

#define N_NODES 100000
#define N_EDGES 1600000
#define NHEAD   8
#define NC      16
#define NEG     0.2f

typedef __attribute__((ext_vector_type(4))) float f32x4;
typedef __attribute__((ext_vector_type(8))) short s16x8;

__device__ __forceinline__ float lrelu(float x) { return x > 0.f ? x : NEG * x; }
__device__ __forceinline__ short bf16rne(float f) {
    unsigned u = __float_as_uint(f);
    return (short)((u + 0x7FFFu + ((u >> 16) & 1u)) >> 16);
}
__device__ __forceinline__ float bf2f(unsigned short u) {
    return __uint_as_float(((unsigned)u) << 16);
}

// ---------- K0: pack W1 (256x64 f32) into bf16 fragment-major layout ----------
__global__ __launch_bounds__(256) void wtrans_kernel(const float* __restrict__ W1,
                                                     float4* __restrict__ Wt) {
    int u = blockIdx.x * 256 + threadIdx.x;   // 2048 units
    int j = u >> 9, ks = (u >> 6) & 7, l = u & 63;
    int colc = j * 16 + (l & 15);
    int k0 = ks * 32 + (l >> 4) * 8;
    union { s16x8 s; float4 f; } pk;
#pragma unroll
    for (int i = 0; i < 8; ++i) pk.s[i] = bf16rne(W1[(size_t)(k0 + i) * 64 + colc]);
    Wt[u] = pk.f;
}

// ---------- K1: h = x@W1 via bf16 MFMA; h stored as bf16 ----------
__global__ __launch_bounds__(256) void gemm1_kernel(
    const float* __restrict__ x, const float4* __restrict__ Wt,
    unsigned short* __restrict__ hb) {
    __shared__ float4 WtL[2048];   // 32 KB, fragment-major
    int tid = threadIdx.x;
#pragma unroll
    for (int i = 0; i < 8; ++i) WtL[tid + i * 256] = Wt[tid + i * 256];
    int w = tid >> 6, lane = tid & 63;
    int n0 = blockIdx.x * 128;
    int r0 = n0 + w * 32 + (lane & 15);
    int r1 = r0 + 16;
    int cr0 = r0 < N_NODES ? r0 : 0;
    int cr1 = r1 < N_NODES ? r1 : 0;
    int koff = (lane >> 4) * 8;
    f32x4 acc[2][4];
#pragma unroll
    for (int r = 0; r < 2; ++r)
#pragma unroll
        for (int j = 0; j < 4; ++j) acc[r][j] = (f32x4)0.f;
    __syncthreads();
#pragma unroll
    for (int ks = 0; ks < 8; ++ks) {
        const float* p0 = x + (size_t)cr0 * 256 + ks * 32 + koff;
        const float* p1 = x + (size_t)cr1 * 256 + ks * 32 + koff;
        float4 a0l = *(const float4*)p0, a0h = *(const float4*)(p0 + 4);
        float4 a1l = *(const float4*)p1, a1h = *(const float4*)(p1 + 4);
        s16x8 A0, A1;
        A0[0] = bf16rne(a0l.x); A0[1] = bf16rne(a0l.y); A0[2] = bf16rne(a0l.z); A0[3] = bf16rne(a0l.w);
        A0[4] = bf16rne(a0h.x); A0[5] = bf16rne(a0h.y); A0[6] = bf16rne(a0h.z); A0[7] = bf16rne(a0h.w);
        A1[0] = bf16rne(a1l.x); A1[1] = bf16rne(a1l.y); A1[2] = bf16rne(a1l.z); A1[3] = bf16rne(a1l.w);
        A1[4] = bf16rne(a1h.x); A1[5] = bf16rne(a1h.y); A1[6] = bf16rne(a1h.z); A1[7] = bf16rne(a1h.w);
#pragma unroll
        for (int j = 0; j < 4; ++j) {
            s16x8 B = *(s16x8*)&WtL[(j * 8 + ks) * 64 + lane];
            acc[0][j] = __builtin_amdgcn_mfma_f32_16x16x32_bf16(A0, B, acc[0][j], 0, 0, 0);
            acc[1][j] = __builtin_amdgcn_mfma_f32_16x16x32_bf16(A1, B, acc[1][j], 0, 0, 0);
        }
    }
    int rbase = (lane >> 4) * 4;
#pragma unroll
    for (int r = 0; r < 2; ++r) {
        int growb = n0 + w * 32 + r * 16 + rbase;
#pragma unroll
        for (int reg = 0; reg < 4; ++reg) {
            int grow = growb + reg;
            if (grow < N_NODES) {
                unsigned short* hp = hb + (size_t)grow * 64 + (lane & 15);
#pragma unroll
                for (int j = 0; j < 4; ++j) hp[j * 16] = (unsigned short)bf16rne(acc[r][j][reg]);
            }
        }
    }
}

// ---------- K2: s,t logits from bf16 h ----------
__global__ __launch_bounds__(256) void st_kernel(const unsigned short* __restrict__ hb,
    const float* __restrict__ a1s, const float* __restrict__ a1d,
    float* __restrict__ s, float* __restrict__ t) {
    int g = blockIdx.x * 256 + threadIdx.x;   // node*8+head
    int hh = g & 7;
    uint4 raw = *(const uint4*)(hb + (size_t)g * 8);
    float f0 = __uint_as_float(raw.x << 16), f1 = __uint_as_float(raw.x & 0xFFFF0000u);
    float f2 = __uint_as_float(raw.y << 16), f3 = __uint_as_float(raw.y & 0xFFFF0000u);
    float f4 = __uint_as_float(raw.z << 16), f5 = __uint_as_float(raw.z & 0xFFFF0000u);
    float f6 = __uint_as_float(raw.w << 16), f7 = __uint_as_float(raw.w & 0xFFFF0000u);
    const float* as = a1s + hh * 8;
    const float* ad = a1d + hh * 8;
    s[g] = f0 * as[0] + f1 * as[1] + f2 * as[2] + f3 * as[3]
         + f4 * as[4] + f5 * as[5] + f6 * as[6] + f7 * as[7];
    t[g] = f0 * ad[0] + f1 * ad[1] + f2 * ad[2] + f3 * ad[3]
         + f4 * ad[4] + f5 * ad[5] + f6 * ad[6] + f7 * ad[7];
}

// ---------- K3: degree histogram ----------
__global__ __launch_bounds__(256) void hist_kernel(const int* __restrict__ edst,
                                                   int* __restrict__ count) {
    int e = blockIdx.x * 256 + threadIdx.x;
    if (e < N_EDGES) atomicAdd(&count[edst[e]], 1);
}

// ---------- K4a: per-chunk exclusive scan (98 blocks x 1024) ----------
__global__ __launch_bounds__(1024) void scan_a(const int* __restrict__ count,
                                               int* __restrict__ part,
                                               int* __restrict__ totals) {
    __shared__ int wsum[16];
    int tid = threadIdx.x, wid = tid >> 6, lane = tid & 63;
    int i = blockIdx.x * 1024 + tid;
    int v = (i < N_NODES) ? count[i] : 0;
    int inc = v;
#pragma unroll
    for (int off = 1; off < 64; off <<= 1) {
        int nb = __shfl_up(inc, off, 64);
        if (lane >= off) inc += nb;
    }
    if (lane == 63) wsum[wid] = inc;
    __syncthreads();
    if (tid == 0) {
        int run = 0;
#pragma unroll
        for (int k = 0; k < 16; ++k) { int tmp = wsum[k]; wsum[k] = run; run += tmp; }
        totals[blockIdx.x] = run;
    }
    __syncthreads();
    if (i < N_NODES) part[i] = inc - v + wsum[wid];
}

// ---------- K4b: add chunk offsets; write rowptr + cursor ----------
__global__ __launch_bounds__(1024) void scan_b(const int* __restrict__ part,
                                               const int* __restrict__ totals,
                                               int* __restrict__ rowptr,
                                               int* __restrict__ cursor) {
    __shared__ int boff;
    if (threadIdx.x == 0) {
        int run = 0;
        for (int k = 0; k < (int)blockIdx.x; ++k) run += totals[k];
        boff = run;
    }
    __syncthreads();
    int i = blockIdx.x * 1024 + threadIdx.x;
    if (i < N_NODES) {
        int v = part[i] + boff;
        rowptr[i] = v;
        cursor[i] = v;
    }
    if (i == 0) rowptr[N_NODES] = N_EDGES;
}

// ---------- K5: scatter edges into CSR ----------
__global__ __launch_bounds__(256) void scatter_kernel(const int* __restrict__ esrc,
    const int* __restrict__ edst, int* __restrict__ cursor, int* __restrict__ col) {
    int e = blockIdx.x * 256 + threadIdx.x;
    if (e >= N_EDGES) return;
    int pos = atomicAdd(&cursor[edst[e]], 1);
    col[pos] = esrc[e];
}

// ---------- K6: layer-1 aggregation, one wave per dst, bf16 h gather ----------
__global__ __launch_bounds__(256) void agg1_kernel(
    const int* __restrict__ rowptr, const int* __restrict__ col,
    const float* __restrict__ s, const float* __restrict__ t,
    const unsigned short* __restrict__ hb, float* __restrict__ h1) {
    int tid = threadIdx.x;
    int d = blockIdx.x * 4 + (tid >> 6);
    int lane = tid & 63, hh = lane >> 3;
    int beg = rowptr[d], end = rowptr[d + 1];
    float tv = t[d * 8 + hh];
    float acc0 = 0.f, acc1 = 0.f, den0 = 0.f, den1 = 0.f;
    int p = beg;
    for (; p + 2 <= end; p += 2) {
        int s0 = col[p], s1 = col[p + 1];
        float e0 = __expf(lrelu(s[s0 * 8 + hh] + tv));
        float e1 = __expf(lrelu(s[s1 * 8 + hh] + tv));
        float v0 = bf2f(hb[(size_t)s0 * 64 + lane]);
        float v1 = bf2f(hb[(size_t)s1 * 64 + lane]);
        acc0 += e0 * v0; den0 += e0;
        acc1 += e1 * v1; den1 += e1;
    }
    if (p < end) {
        int s0 = col[p];
        float e0 = __expf(lrelu(s[s0 * 8 + hh] + tv));
        acc0 += e0 * bf2f(hb[(size_t)s0 * 64 + lane]);
        den0 += e0;
    }
    float v = (acc0 + acc1) / (den0 + den1 + 1e-16f);
    h1[(size_t)d * 64 + lane] = v > 0.f ? v : __expf(v) - 1.f;
}

// ---------- K7: h2 = h1@W2 (bf16 out); s2,t2 fused ----------
__global__ __launch_bounds__(256) void gemm2_kernel(
    const float* __restrict__ h1, const float* __restrict__ W2,
    const float* __restrict__ a2s, const float* __restrict__ a2d,
    unsigned short* __restrict__ h2b, float* __restrict__ s2, float* __restrict__ t2) {
    __shared__ float Wl[64 * NC];       // 4 KB
    __shared__ float h1l[16 * 65];      // padded
    int tid = threadIdx.x;
    ((float4*)Wl)[tid] = ((const float4*)W2)[tid];
    {
        float4 raw = ((const float4*)h1)[(size_t)blockIdx.x * 256 + tid];
        int f = tid * 4, rr = f >> 6, kk = f & 63;
        float* dp = &h1l[rr * 65 + kk];
        dp[0] = raw.x; dp[1] = raw.y; dp[2] = raw.z; dp[3] = raw.w;
    }
    __syncthreads();
    int c = tid & 15, r = tid >> 4;
    int n = blockIdx.x * 16 + r;
    float a = 0.f;
#pragma unroll 16
    for (int k = 0; k < 64; ++k) a += h1l[r * 65 + k] * Wl[k * NC + c];
    h2b[(size_t)n * NC + c] = (unsigned short)bf16rne(a);
    float vs = a * a2s[c];
    float vt = a * a2d[c];
#pragma unroll
    for (int o = 1; o < 16; o <<= 1) {
        vs += __shfl_xor(vs, o, 64);
        vt += __shfl_xor(vt, o, 64);
    }
    if (c == 0) { s2[n] = vs; t2[n] = vt; }
}

// ---------- K8: layer-2 aggregation + fused log_softmax, 16 lanes per dst ----------
__global__ __launch_bounds__(256) void agg2_kernel(
    const int* __restrict__ rowptr, const int* __restrict__ col,
    const float* __restrict__ s2, const float* __restrict__ t2,
    const unsigned short* __restrict__ h2b, float* __restrict__ out) {
    int tid = threadIdx.x;
    int d = blockIdx.x * 16 + (tid >> 4);
    int c = tid & 15;
    int beg = rowptr[d], end = rowptr[d + 1];
    float tv = t2[d];
    float acc0 = 0.f, acc1 = 0.f, den0 = 0.f, den1 = 0.f;
    int p = beg;
    for (; p + 2 <= end; p += 2) {
        int s0 = col[p], s1 = col[p + 1];
        float e0 = __expf(lrelu(s2[s0] + tv));
        float e1 = __expf(lrelu(s2[s1] + tv));
        float v0 = bf2f(h2b[(size_t)s0 * 16 + c]);
        float v1 = bf2f(h2b[(size_t)s1 * 16 + c]);
        acc0 += e0 * v0; den0 += e0;
        acc1 += e1 * v1; den1 += e1;
    }
    if (p < end) {
        int s0 = col[p];
        float e0 = __expf(lrelu(s2[s0] + tv));
        acc0 += e0 * bf2f(h2b[(size_t)s0 * 16 + c]);
        den0 += e0;
    }
    float v = (acc0 + acc1) / (den0 + den1 + 1e-16f);
    float mx = v;
#pragma unroll
    for (int o = 1; o < 16; o <<= 1) mx = fmaxf(mx, __shfl_xor(mx, o, 64));
    float e = __expf(v - mx), sum = e;
#pragma unroll
    for (int o = 1; o < 16; o <<= 1) sum += __shfl_xor(sum, o, 64);
    out[(size_t)d * NC + c] = v - mx - __logf(sum);
}

extern "C" void kernel_launch(void* const* d_in, const int* in_sizes, int n_in,
                              void* d_out, int out_size, void* d_ws, size_t ws_size,
                              hipStream_t stream) {
    const float* x   = (const float*)d_in[0];
    const int*  eidx = (const int*)d_in[1];   // [2, E] int32
    const float* W1  = (const float*)d_in[2];
    const float* a1s = (const float*)d_in[3];
    const float* a1d = (const float*)d_in[4];
    const float* W2  = (const float*)d_in[5];
    const float* a2s = (const float*)d_in[6];
    const float* a2d = (const float*)d_in[7];
    float* out = (float*)d_out;
    const int* esrc = eidx;
    const int* edst = eidx + N_EDGES;

    // ---- workspace layout ----
    char* p = (char*)d_ws;
    int*    count  = (int*)p;    p += (size_t)N_NODES * 4;          // zeroed
    int*    part   = (int*)p;    p += (size_t)N_NODES * 4;
    int*    totals = (int*)p;    p += (size_t)128 * 4;
    int*    cursor = (int*)p;    p += (size_t)N_NODES * 4;
    int*    rowptr = (int*)p;    p += (size_t)(N_NODES + 4) * 4;
    int*    col    = (int*)p;    p += (size_t)N_EDGES * 4;
    float4* Wt     = (float4*)p; p += (size_t)2048 * 16;
    unsigned short* hb = (unsigned short*)p; p += (size_t)N_NODES * 64 * 2;
    float*  s      = (float*)p;  p += (size_t)N_NODES * 8 * 4;
    float*  t      = (float*)p;  p += (size_t)N_NODES * 8 * 4;
    float*  h1     = (float*)p;  p += (size_t)N_NODES * 64 * 4;
    unsigned short* h2b = (unsigned short*)p; p += (size_t)N_NODES * NC * 2;
    float*  s2     = (float*)p;  p += (size_t)N_NODES * 4;
    float*  t2     = (float*)p;  p += (size_t)N_NODES * 4;

    hipMemsetAsync(count, 0, (size_t)N_NODES * 4, stream);

    wtrans_kernel<<<8, 256, 0, stream>>>(W1, Wt);
    hist_kernel<<<N_EDGES / 256, 256, 0, stream>>>(edst, count);
    gemm1_kernel<<<(N_NODES + 127) / 128, 256, 0, stream>>>(x, Wt, hb);
    scan_a<<<(N_NODES + 1023) / 1024, 1024, 0, stream>>>(count, part, totals);
    scan_b<<<(N_NODES + 1023) / 1024, 1024, 0, stream>>>(part, totals, rowptr, cursor);
    st_kernel<<<(N_NODES * 8) / 256, 256, 0, stream>>>(hb, a1s, a1d, s, t);
    scatter_kernel<<<N_EDGES / 256, 256, 0, stream>>>(esrc, edst, cursor, col);
    agg1_kernel<<<N_NODES / 4, 256, 0, stream>>>(rowptr, col, s, t, hb, h1);
    gemm2_kernel<<<N_NODES / 16, 256, 0, stream>>>(h1, W2, a2s, a2d, h2b, s2, t2);
    agg2_kernel<<<N_NODES / 16, 256, 0, stream>>>(rowptr, col, s2, t2, h2b, out);
}

// Round 5
// 395.059 us; speedup vs baseline: 3.1454x; 1.3432x over previous
//
#include <hip/hip_runtime.h>
#include <math.h>

#define N_NODES 100000
#define N_EDGES 1600000
#define NHEAD   8
#define NC      16
#define NEG     0.2f
#define BSH     9                 // 512 dst nodes per bucket
#define NBUCK   196               // ceil(100000/512)
#define TILE    8192              // edges per binning block
#define NBLK    196               // ceil(1600000/8192)
#define CAP     10240             // max edges per bucket (22 sigma margin)

typedef __attribute__((ext_vector_type(4))) float f32x4;
typedef __attribute__((ext_vector_type(8))) short s16x8;

__device__ __forceinline__ float lrelu(float x) { return x > 0.f ? x : NEG * x; }
__device__ __forceinline__ short bf16rne(float f) {
    unsigned u = __float_as_uint(f);
    return (short)((u + 0x7FFFu + ((u >> 16) & 1u)) >> 16);
}
__device__ __forceinline__ float bf2f(unsigned short u) {
    return __uint_as_float(((unsigned)u) << 16);
}

// ---------- K0: pack W1 (256x64 f32) into bf16 fragment-major layout ----------
__global__ __launch_bounds__(256) void wtrans_kernel(const float* __restrict__ W1,
                                                     float4* __restrict__ Wt) {
    int u = blockIdx.x * 256 + threadIdx.x;   // 2048 units
    int j = u >> 9, ks = (u >> 6) & 7, l = u & 63;
    int colc = j * 16 + (l & 15);
    int k0 = ks * 32 + (l >> 4) * 8;
    union { s16x8 s; float4 f; } pk;
#pragma unroll
    for (int i = 0; i < 8; ++i) pk.s[i] = bf16rne(W1[(size_t)(k0 + i) * 64 + colc]);
    Wt[u] = pk.f;
}

// ---------- K1: h = x@W1 via bf16 MFMA; h stored as bf16 ----------
__global__ __launch_bounds__(256) void gemm1_kernel(
    const float* __restrict__ x, const float4* __restrict__ Wt,
    unsigned short* __restrict__ hb) {
    __shared__ float4 WtL[2048];   // 32 KB, fragment-major
    int tid = threadIdx.x;
#pragma unroll
    for (int i = 0; i < 8; ++i) WtL[tid + i * 256] = Wt[tid + i * 256];
    int w = tid >> 6, lane = tid & 63;
    int n0 = blockIdx.x * 128;
    int r0 = n0 + w * 32 + (lane & 15);
    int r1 = r0 + 16;
    int cr0 = r0 < N_NODES ? r0 : 0;
    int cr1 = r1 < N_NODES ? r1 : 0;
    int koff = (lane >> 4) * 8;
    f32x4 acc[2][4];
#pragma unroll
    for (int r = 0; r < 2; ++r)
#pragma unroll
        for (int j = 0; j < 4; ++j) acc[r][j] = (f32x4)0.f;
    __syncthreads();
#pragma unroll
    for (int ks = 0; ks < 8; ++ks) {
        const float* p0 = x + (size_t)cr0 * 256 + ks * 32 + koff;
        const float* p1 = x + (size_t)cr1 * 256 + ks * 32 + koff;
        float4 a0l = *(const float4*)p0, a0h = *(const float4*)(p0 + 4);
        float4 a1l = *(const float4*)p1, a1h = *(const float4*)(p1 + 4);
        s16x8 A0, A1;
        A0[0] = bf16rne(a0l.x); A0[1] = bf16rne(a0l.y); A0[2] = bf16rne(a0l.z); A0[3] = bf16rne(a0l.w);
        A0[4] = bf16rne(a0h.x); A0[5] = bf16rne(a0h.y); A0[6] = bf16rne(a0h.z); A0[7] = bf16rne(a0h.w);
        A1[0] = bf16rne(a1l.x); A1[1] = bf16rne(a1l.y); A1[2] = bf16rne(a1l.z); A1[3] = bf16rne(a1l.w);
        A1[4] = bf16rne(a1h.x); A1[5] = bf16rne(a1h.y); A1[6] = bf16rne(a1h.z); A1[7] = bf16rne(a1h.w);
#pragma unroll
        for (int j = 0; j < 4; ++j) {
            s16x8 B = *(s16x8*)&WtL[(j * 8 + ks) * 64 + lane];
            acc[0][j] = __builtin_amdgcn_mfma_f32_16x16x32_bf16(A0, B, acc[0][j], 0, 0, 0);
            acc[1][j] = __builtin_amdgcn_mfma_f32_16x16x32_bf16(A1, B, acc[1][j], 0, 0, 0);
        }
    }
    int rbase = (lane >> 4) * 4;
#pragma unroll
    for (int r = 0; r < 2; ++r) {
        int growb = n0 + w * 32 + r * 16 + rbase;
#pragma unroll
        for (int reg = 0; reg < 4; ++reg) {
            int grow = growb + reg;
            if (grow < N_NODES) {
                unsigned short* hp = hb + (size_t)grow * 64 + (lane & 15);
#pragma unroll
                for (int j = 0; j < 4; ++j) hp[j * 16] = (unsigned short)bf16rne(acc[r][j][reg]);
            }
        }
    }
}

// ---------- K2: s,t logits from bf16 h ----------
__global__ __launch_bounds__(256) void st_kernel(const unsigned short* __restrict__ hb,
    const float* __restrict__ a1s, const float* __restrict__ a1d,
    float* __restrict__ s, float* __restrict__ t) {
    int g = blockIdx.x * 256 + threadIdx.x;   // node*8+head
    int hh = g & 7;
    uint4 raw = *(const uint4*)(hb + (size_t)g * 8);
    float f0 = __uint_as_float(raw.x << 16), f1 = __uint_as_float(raw.x & 0xFFFF0000u);
    float f2 = __uint_as_float(raw.y << 16), f3 = __uint_as_float(raw.y & 0xFFFF0000u);
    float f4 = __uint_as_float(raw.z << 16), f5 = __uint_as_float(raw.z & 0xFFFF0000u);
    float f6 = __uint_as_float(raw.w << 16), f7 = __uint_as_float(raw.w & 0xFFFF0000u);
    const float* as = a1s + hh * 8;
    const float* ad = a1d + hh * 8;
    s[g] = f0 * as[0] + f1 * as[1] + f2 * as[2] + f3 * as[3]
         + f4 * as[4] + f5 * as[5] + f6 * as[6] + f7 * as[7];
    t[g] = f0 * ad[0] + f1 * ad[1] + f2 * ad[2] + f3 * ad[3]
         + f4 * ad[4] + f5 * ad[5] + f6 * ad[6] + f7 * ad[7];
}

// ---------- K3: bucket histogram (LDS pre-reduction, 39K global atomics) ----------
__global__ __launch_bounds__(256) void bhist_kernel(const int* __restrict__ edst,
                                                    int* __restrict__ bhist) {
    __shared__ int lh[256];
    int tid = threadIdx.x;
    lh[tid] = 0;
    __syncthreads();
    int e0 = blockIdx.x * TILE;
#pragma unroll
    for (int k = 0; k < TILE / 256; ++k) {
        int e = e0 + k * 256 + tid;
        if (e < N_EDGES) atomicAdd(&lh[edst[e] >> BSH], 1);
    }
    __syncthreads();
    if (lh[tid]) atomicAdd(&bhist[tid], lh[tid]);
}

// ---------- K4: scan 196 bucket totals -> bbase (exclusive) + bcur ----------
__global__ __launch_bounds__(256) void bscan_kernel(const int* __restrict__ bhist,
                                                    int* __restrict__ bbase,
                                                    int* __restrict__ bcur) {
    __shared__ int sc[256];
    int tid = threadIdx.x;
    int v = bhist[tid];
    sc[tid] = v;
    __syncthreads();
    for (int off = 1; off < 256; off <<= 1) {
        int a = (tid >= off) ? sc[tid - off] : 0;
        __syncthreads();
        sc[tid] += a;
        __syncthreads();
    }
    int excl = sc[tid] - v;
    bbase[tid] = excl;
    bcur[tid] = excl;
    if (tid == 255) bbase[256] = sc[255];
}

// ---------- K5: binned scatter: edges -> bucket-grouped tmp (packed src|dl<<17) ----------
__global__ __launch_bounds__(256) void binscatter_kernel(
    const int* __restrict__ esrc, const int* __restrict__ edst,
    int* __restrict__ bcur, unsigned* __restrict__ tmp) {
    __shared__ unsigned buf[TILE];      // 32 KB
    __shared__ int hist[256], lbase[256], cur[256], gbase[256], sc[256];
    int tid = threadIdx.x;
    hist[tid] = 0; cur[tid] = 0;
    __syncthreads();
    int e0 = blockIdx.x * TILE;
#pragma unroll
    for (int k = 0; k < TILE / 256; ++k) {
        int e = e0 + k * 256 + tid;
        if (e < N_EDGES) atomicAdd(&hist[edst[e] >> BSH], 1);
    }
    __syncthreads();
    {   // exclusive scan of hist -> lbase
        int v = hist[tid];
        sc[tid] = v;
        __syncthreads();
        for (int off = 1; off < 256; off <<= 1) {
            int a = (tid >= off) ? sc[tid - off] : 0;
            __syncthreads();
            sc[tid] += a;
            __syncthreads();
        }
        lbase[tid] = sc[tid] - v;
    }
    gbase[tid] = hist[tid] ? atomicAdd(&bcur[tid], hist[tid]) : 0;
    __syncthreads();
    // place edges into LDS bucket-grouped order
#pragma unroll
    for (int k = 0; k < TILE / 256; ++k) {
        int e = e0 + k * 256 + tid;
        if (e < N_EDGES) {
            int d = edst[e];
            int b = d >> BSH;
            int p = lbase[b] + atomicAdd(&cur[b], 1);
            buf[p] = (unsigned)esrc[e] | ((unsigned)(d & ((1 << BSH) - 1)) << 17);
        }
    }
    __syncthreads();
    // flush contiguous runs per bucket (wave-cooperative)
    int w = tid >> 6, lane = tid & 63;
    for (int b = w; b < NBUCK; b += 4) {
        int L = hist[b], lb = lbase[b], gb = gbase[b];
        for (int i = lane; i < L; i += 64) tmp[gb + i] = buf[lb + i];
    }
}

// ---------- K6: per-bucket LDS counting sort -> final col + rowptr ----------
__global__ __launch_bounds__(256) void bsort_kernel(
    const int* __restrict__ bbase, const unsigned* __restrict__ tmp,
    int* __restrict__ rowptr, int* __restrict__ col) {
    __shared__ unsigned sorted[CAP];    // 40 KB
    __shared__ int cnt[512], excl[512], pair[256];
    int tid = threadIdx.x;
    int b = blockIdx.x;
    int lo = bbase[b], hi = bbase[b + 1], L = hi - lo;
    cnt[tid] = 0; cnt[tid + 256] = 0;
    __syncthreads();
    for (int i = tid; i < L; i += 256) atomicAdd(&cnt[tmp[lo + i] >> 17], 1);
    __syncthreads();
    // scan 512 via pairs
    int c0 = cnt[2 * tid], c1 = cnt[2 * tid + 1];
    pair[tid] = c0 + c1;
    __syncthreads();
    for (int off = 1; off < 256; off <<= 1) {
        int a = (tid >= off) ? pair[tid - off] : 0;
        __syncthreads();
        pair[tid] += a;
        __syncthreads();
    }
    int pexcl = pair[tid] - (c0 + c1);
    excl[2 * tid] = pexcl;
    excl[2 * tid + 1] = pexcl + c0;
    __syncthreads();
    // rowptr (covers rowptr[N_NODES] via b=195, dl=160)
    for (int dl = tid; dl < 512; dl += 256) {
        int node = (b << BSH) + dl;
        if (node <= N_NODES) rowptr[node] = lo + excl[dl];
    }
    // cursors = excl (reuse cnt)
    cnt[2 * tid] = excl[2 * tid];
    cnt[2 * tid + 1] = excl[2 * tid + 1];
    __syncthreads();
    for (int i = tid; i < L; i += 256) {
        unsigned v = tmp[lo + i];
        int p = atomicAdd(&cnt[v >> 17], 1);
        sorted[p] = v & 0x1FFFFu;
    }
    __syncthreads();
    for (int i = tid; i < L; i += 256) col[lo + i] = (int)sorted[i];
}

// ---------- K7: layer-1 aggregation, one wave per dst, 4 gather chains ----------
__global__ __launch_bounds__(256) void agg1_kernel(
    const int* __restrict__ rowptr, const int* __restrict__ col,
    const float* __restrict__ s, const float* __restrict__ t,
    const unsigned short* __restrict__ hb, float* __restrict__ h1) {
    int tid = threadIdx.x;
    int d = blockIdx.x * 4 + (tid >> 6);
    int lane = tid & 63, hh = lane >> 3;
    int beg = rowptr[d], end = rowptr[d + 1];
    float tv = t[d * 8 + hh];
    float acc0 = 0.f, acc1 = 0.f, acc2 = 0.f, acc3 = 0.f;
    float den0 = 0.f, den1 = 0.f, den2 = 0.f, den3 = 0.f;
    int p = beg;
    for (; p + 4 <= end; p += 4) {
        int s0 = col[p], s1 = col[p + 1], s2 = col[p + 2], s3 = col[p + 3];
        float e0 = __expf(lrelu(s[s0 * 8 + hh] + tv));
        float e1 = __expf(lrelu(s[s1 * 8 + hh] + tv));
        float e2 = __expf(lrelu(s[s2 * 8 + hh] + tv));
        float e3 = __expf(lrelu(s[s3 * 8 + hh] + tv));
        float v0 = bf2f(hb[(size_t)s0 * 64 + lane]);
        float v1 = bf2f(hb[(size_t)s1 * 64 + lane]);
        float v2 = bf2f(hb[(size_t)s2 * 64 + lane]);
        float v3 = bf2f(hb[(size_t)s3 * 64 + lane]);
        acc0 += e0 * v0; den0 += e0;
        acc1 += e1 * v1; den1 += e1;
        acc2 += e2 * v2; den2 += e2;
        acc3 += e3 * v3; den3 += e3;
    }
    for (; p < end; ++p) {
        int s0 = col[p];
        float e0 = __expf(lrelu(s[s0 * 8 + hh] + tv));
        acc0 += e0 * bf2f(hb[(size_t)s0 * 64 + lane]);
        den0 += e0;
    }
    float v = (acc0 + acc1 + acc2 + acc3) / (den0 + den1 + den2 + den3 + 1e-16f);
    h1[(size_t)d * 64 + lane] = v > 0.f ? v : __expf(v) - 1.f;
}

// ---------- K8: h2 = h1@W2 (bf16 out); s2,t2 fused ----------
__global__ __launch_bounds__(256) void gemm2_kernel(
    const float* __restrict__ h1, const float* __restrict__ W2,
    const float* __restrict__ a2s, const float* __restrict__ a2d,
    unsigned short* __restrict__ h2b, float* __restrict__ s2, float* __restrict__ t2) {
    __shared__ float Wl[64 * NC];       // 4 KB
    __shared__ float h1l[16 * 65];      // padded
    int tid = threadIdx.x;
    ((float4*)Wl)[tid] = ((const float4*)W2)[tid];
    {
        float4 raw = ((const float4*)h1)[(size_t)blockIdx.x * 256 + tid];
        int f = tid * 4, rr = f >> 6, kk = f & 63;
        float* dp = &h1l[rr * 65 + kk];
        dp[0] = raw.x; dp[1] = raw.y; dp[2] = raw.z; dp[3] = raw.w;
    }
    __syncthreads();
    int c = tid & 15, r = tid >> 4;
    int n = blockIdx.x * 16 + r;
    float a = 0.f;
#pragma unroll 16
    for (int k = 0; k < 64; ++k) a += h1l[r * 65 + k] * Wl[k * NC + c];
    h2b[(size_t)n * NC + c] = (unsigned short)bf16rne(a);
    float vs = a * a2s[c];
    float vt = a * a2d[c];
#pragma unroll
    for (int o = 1; o < 16; o <<= 1) {
        vs += __shfl_xor(vs, o, 64);
        vt += __shfl_xor(vt, o, 64);
    }
    if (c == 0) { s2[n] = vs; t2[n] = vt; }
}

// ---------- K9: layer-2 aggregation + fused log_softmax, 16 lanes per dst ----------
__global__ __launch_bounds__(256) void agg2_kernel(
    const int* __restrict__ rowptr, const int* __restrict__ col,
    const float* __restrict__ s2, const float* __restrict__ t2,
    const unsigned short* __restrict__ h2b, float* __restrict__ out) {
    int tid = threadIdx.x;
    int d = blockIdx.x * 16 + (tid >> 4);
    int c = tid & 15;
    int beg = rowptr[d], end = rowptr[d + 1];
    float tv = t2[d];
    float acc0 = 0.f, acc1 = 0.f, den0 = 0.f, den1 = 0.f;
    int p = beg;
    for (; p + 2 <= end; p += 2) {
        int s0 = col[p], s1 = col[p + 1];
        float e0 = __expf(lrelu(s2[s0] + tv));
        float e1 = __expf(lrelu(s2[s1] + tv));
        float v0 = bf2f(h2b[(size_t)s0 * 16 + c]);
        float v1 = bf2f(h2b[(size_t)s1 * 16 + c]);
        acc0 += e0 * v0; den0 += e0;
        acc1 += e1 * v1; den1 += e1;
    }
    if (p < end) {
        int s0 = col[p];
        float e0 = __expf(lrelu(s2[s0] + tv));
        acc0 += e0 * bf2f(h2b[(size_t)s0 * 16 + c]);
        den0 += e0;
    }
    float v = (acc0 + acc1) / (den0 + den1 + 1e-16f);
    float mx = v;
#pragma unroll
    for (int o = 1; o < 16; o <<= 1) mx = fmaxf(mx, __shfl_xor(mx, o, 64));
    float e = __expf(v - mx), sum = e;
#pragma unroll
    for (int o = 1; o < 16; o <<= 1) sum += __shfl_xor(sum, o, 64);
    out[(size_t)d * NC + c] = v - mx - __logf(sum);
}

extern "C" void kernel_launch(void* const* d_in, const int* in_sizes, int n_in,
                              void* d_out, int out_size, void* d_ws, size_t ws_size,
                              hipStream_t stream) {
    const float* x   = (const float*)d_in[0];
    const int*  eidx = (const int*)d_in[1];   // [2, E] int32
    const float* W1  = (const float*)d_in[2];
    const float* a1s = (const float*)d_in[3];
    const float* a1d = (const float*)d_in[4];
    const float* W2  = (const float*)d_in[5];
    const float* a2s = (const float*)d_in[6];
    const float* a2d = (const float*)d_in[7];
    float* out = (float*)d_out;
    const int* esrc = eidx;
    const int* edst = eidx + N_EDGES;

    // ---- workspace layout ----
    char* p = (char*)d_ws;
    int*      bhist  = (int*)p;      p += 256 * 4;                  // zeroed (1 KB)
    int*      bbase  = (int*)p;      p += 260 * 4;
    int*      bcur   = (int*)p;      p += 256 * 4;
    unsigned* tmp    = (unsigned*)p; p += (size_t)N_EDGES * 4;
    int*      col    = (int*)p;      p += (size_t)N_EDGES * 4;
    int*      rowptr = (int*)p;      p += (size_t)(N_NODES + 4) * 4;
    float4*   Wt     = (float4*)p;   p += (size_t)2048 * 16;
    unsigned short* hb = (unsigned short*)p; p += (size_t)N_NODES * 64 * 2;
    float*    s      = (float*)p;    p += (size_t)N_NODES * 8 * 4;
    float*    t      = (float*)p;    p += (size_t)N_NODES * 8 * 4;
    float*    h1     = (float*)p;    p += (size_t)N_NODES * 64 * 4;
    unsigned short* h2b = (unsigned short*)p; p += (size_t)N_NODES * NC * 2;
    float*    s2     = (float*)p;    p += (size_t)N_NODES * 4;
    float*    t2     = (float*)p;    p += (size_t)N_NODES * 4;

    hipMemsetAsync(bhist, 0, 256 * 4, stream);

    wtrans_kernel<<<8, 256, 0, stream>>>(W1, Wt);
    bhist_kernel<<<NBLK, 256, 0, stream>>>(edst, bhist);
    gemm1_kernel<<<(N_NODES + 127) / 128, 256, 0, stream>>>(x, Wt, hb);
    bscan_kernel<<<1, 256, 0, stream>>>(bhist, bbase, bcur);
    st_kernel<<<(N_NODES * 8) / 256, 256, 0, stream>>>(hb, a1s, a1d, s, t);
    binscatter_kernel<<<NBLK, 256, 0, stream>>>(esrc, edst, bcur, tmp);
    bsort_kernel<<<NBUCK, 256, 0, stream>>>(bbase, tmp, rowptr, col);
    agg1_kernel<<<N_NODES / 4, 256, 0, stream>>>(rowptr, col, s, t, hb, h1);
    gemm2_kernel<<<N_NODES / 16, 256, 0, stream>>>(h1, W2, a2s, a2d, h2b, s2, t2);
    agg2_kernel<<<N_NODES / 16, 256, 0, stream>>>(rowptr, col, s2, t2, h2b, out);
}

// Round 6
// 347.274 us; speedup vs baseline: 3.5782x; 1.1376x over previous
//
#include <hip/hip_runtime.h>
#include <math.h>

#define N_NODES 100000
#define N_EDGES 1600000
#define NHEAD   8
#define NC      16
#define NEG     0.2f
#define BSH     8                 // 256 dst nodes per bucket
#define NBUCK   391               // ceil(100000/256)
#define CAP     5120              // slab capacity (mean 4092, sigma 64 -> +16 sigma)
#define TILE2   4096              // edges per binning block
#define NBLK2   391               // ceil(1600000/4096)

typedef __attribute__((ext_vector_type(4))) float f32x4;
typedef __attribute__((ext_vector_type(8))) short s16x8;

__device__ __forceinline__ float lrelu(float x) { return x > 0.f ? x : NEG * x; }
__device__ __forceinline__ short bf16rne(float f) {
    unsigned u = __float_as_uint(f);
    return (short)((u + 0x7FFFu + ((u >> 16) & 1u)) >> 16);
}
__device__ __forceinline__ float bf2f(unsigned short u) {
    return __uint_as_float(((unsigned)u) << 16);
}

// ---------- K0: pack W1 (256x64 f32) into bf16 fragment-major layout ----------
__global__ __launch_bounds__(256) void wtrans_kernel(const float* __restrict__ W1,
                                                     float4* __restrict__ Wt) {
    int u = blockIdx.x * 256 + threadIdx.x;   // 2048 units
    int j = u >> 9, ks = (u >> 6) & 7, l = u & 63;
    int colc = j * 16 + (l & 15);
    int k0 = ks * 32 + (l >> 4) * 8;
    union { s16x8 s; float4 f; } pk;
#pragma unroll
    for (int i = 0; i < 8; ++i) pk.s[i] = bf16rne(W1[(size_t)(k0 + i) * 64 + colc]);
    Wt[u] = pk.f;
}

// ---------- K1: h = x@W1 via bf16 MFMA; h->bf16; s,t fused from f32 acc ----------
__global__ __launch_bounds__(256) void gemm1_kernel(
    const float* __restrict__ x, const float4* __restrict__ Wt,
    const float* __restrict__ a1s, const float* __restrict__ a1d,
    unsigned short* __restrict__ hb, float* __restrict__ s, float* __restrict__ t) {
    __shared__ float4 WtL[2048];   // 32 KB, fragment-major
    int tid = threadIdx.x;
#pragma unroll
    for (int i = 0; i < 8; ++i) WtL[tid + i * 256] = Wt[tid + i * 256];
    int w = tid >> 6, lane = tid & 63;
    int n0 = blockIdx.x * 128;
    int r0 = n0 + w * 32 + (lane & 15);
    int r1 = r0 + 16;
    int cr0 = r0 < N_NODES ? r0 : 0;
    int cr1 = r1 < N_NODES ? r1 : 0;
    int koff = (lane >> 4) * 8;
    f32x4 acc[2][4];
#pragma unroll
    for (int r = 0; r < 2; ++r)
#pragma unroll
        for (int j = 0; j < 4; ++j) acc[r][j] = (f32x4)0.f;
    __syncthreads();
#pragma unroll
    for (int ks = 0; ks < 8; ++ks) {
        const float* p0 = x + (size_t)cr0 * 256 + ks * 32 + koff;
        const float* p1 = x + (size_t)cr1 * 256 + ks * 32 + koff;
        float4 a0l = *(const float4*)p0, a0h = *(const float4*)(p0 + 4);
        float4 a1l = *(const float4*)p1, a1h = *(const float4*)(p1 + 4);
        s16x8 A0, A1;
        A0[0] = bf16rne(a0l.x); A0[1] = bf16rne(a0l.y); A0[2] = bf16rne(a0l.z); A0[3] = bf16rne(a0l.w);
        A0[4] = bf16rne(a0h.x); A0[5] = bf16rne(a0h.y); A0[6] = bf16rne(a0h.z); A0[7] = bf16rne(a0h.w);
        A1[0] = bf16rne(a1l.x); A1[1] = bf16rne(a1l.y); A1[2] = bf16rne(a1l.z); A1[3] = bf16rne(a1l.w);
        A1[4] = bf16rne(a1h.x); A1[5] = bf16rne(a1h.y); A1[6] = bf16rne(a1h.z); A1[7] = bf16rne(a1h.w);
#pragma unroll
        for (int j = 0; j < 4; ++j) {
            s16x8 B = *(s16x8*)&WtL[(j * 8 + ks) * 64 + lane];
            acc[0][j] = __builtin_amdgcn_mfma_f32_16x16x32_bf16(A0, B, acc[0][j], 0, 0, 0);
            acc[1][j] = __builtin_amdgcn_mfma_f32_16x16x32_bf16(A1, B, acc[1][j], 0, 0, 0);
        }
    }
    // epilogue: D layout col=lane&15 + 16j, row=(lane>>4)*4+reg
    float asv[4], adv[4];
#pragma unroll
    for (int j = 0; j < 4; ++j) {
        int c = j * 16 + (lane & 15);
        asv[j] = a1s[c]; adv[j] = a1d[c];
    }
    int rbase = (lane >> 4) * 4;
#pragma unroll
    for (int r = 0; r < 2; ++r) {
#pragma unroll
        for (int reg = 0; reg < 4; ++reg) {
            int grow = n0 + w * 32 + r * 16 + rbase + reg;
            bool live = grow < N_NODES;
            unsigned short* hp = hb + (size_t)grow * 64 + (lane & 15);
#pragma unroll
            for (int j = 0; j < 4; ++j) {
                float hv = acc[r][j][reg];
                if (live) hp[j * 16] = (unsigned short)bf16rne(hv);
                float ps = hv * asv[j];
                float pt = hv * adv[j];
                ps += __shfl_xor(ps, 1, 64); ps += __shfl_xor(ps, 2, 64); ps += __shfl_xor(ps, 4, 64);
                pt += __shfl_xor(pt, 1, 64); pt += __shfl_xor(pt, 2, 64); pt += __shfl_xor(pt, 4, 64);
                if ((lane & 7) == 0 && live) {
                    int head = 2 * j + ((lane >> 3) & 1);
                    s[grow * 8 + head] = ps;
                    t[grow * 8 + head] = pt;
                }
            }
        }
    }
}

// ---------- K2: binned scatter into per-bucket slabs (no pre-histogram) ----------
__global__ __launch_bounds__(512) void binscatter_kernel(
    const int* __restrict__ esrc, const int* __restrict__ edst,
    int* __restrict__ bcur, unsigned* __restrict__ tmp) {
    __shared__ unsigned buf[TILE2];              // 16 KB
    __shared__ int hist[512], lbase[512], cur[512], gbase[512];
    int tid = threadIdx.x;
    hist[tid] = 0; cur[tid] = 0;
    __syncthreads();
    int e0 = blockIdx.x * TILE2;
#pragma unroll
    for (int k = 0; k < TILE2 / 512; ++k) {
        int e = e0 + k * 512 + tid;
        if (e < N_EDGES) atomicAdd(&hist[edst[e] >> BSH], 1);
    }
    __syncthreads();
    int v = hist[tid];
    lbase[tid] = v;
    __syncthreads();
    for (int off = 1; off < 512; off <<= 1) {
        int a = (tid >= off) ? lbase[tid - off] : 0;
        __syncthreads();
        lbase[tid] += a;
        __syncthreads();
    }
    lbase[tid] -= v;                              // exclusive
    gbase[tid] = v ? atomicAdd(&bcur[tid], v) : 0;
    __syncthreads();
#pragma unroll
    for (int k = 0; k < TILE2 / 512; ++k) {
        int e = e0 + k * 512 + tid;
        if (e < N_EDGES) {
            int d = edst[e];
            int b = d >> BSH;
            int p = lbase[b] + atomicAdd(&cur[b], 1);
            buf[p] = (unsigned)esrc[e] | ((unsigned)(d & ((1 << BSH) - 1)) << 17);
        }
    }
    __syncthreads();
    int w = tid >> 6, lane = tid & 63;
    for (int b = w; b < 512; b += 8) {
        int L = hist[b];
        if (!L) continue;
        int lb = lbase[b];
        size_t base = (size_t)b * CAP + gbase[b];
        for (int i = lane; i < L; i += 64) tmp[base + i] = buf[lb + i];
    }
}

// ---------- K3: per-bucket LDS counting sort -> col slab + rowbeg/rowend ----------
__global__ __launch_bounds__(256) void bsort_kernel(
    const int* __restrict__ bcur, const unsigned* __restrict__ tmp,
    int* __restrict__ rowbeg, int* __restrict__ rowend, int* __restrict__ colslab) {
    __shared__ unsigned sorted[CAP];              // 20 KB
    __shared__ int cnt[256], scn[256];
    int tid = threadIdx.x, b = blockIdx.x;
    int L = bcur[b];
    const unsigned* tb = tmp + (size_t)b * CAP;
    cnt[tid] = 0;
    __syncthreads();
    for (int i = tid; i < L; i += 256) atomicAdd(&cnt[tb[i] >> 17], 1);
    __syncthreads();
    int v = cnt[tid];
    scn[tid] = v;
    __syncthreads();
    for (int off = 1; off < 256; off <<= 1) {
        int a = (tid >= off) ? scn[tid - off] : 0;
        __syncthreads();
        scn[tid] += a;
        __syncthreads();
    }
    int ex = scn[tid] - v;
    int node = (b << BSH) + tid;
    if (node < N_NODES) {
        rowbeg[node] = b * CAP + ex;
        rowend[node] = b * CAP + ex + v;
    }
    cnt[tid] = ex;                                // cursors
    __syncthreads();
    for (int i = tid; i < L; i += 256) {
        unsigned u = tb[i];
        int p = atomicAdd(&cnt[u >> 17], 1);
        sorted[p] = u & 0x1FFFFu;
    }
    __syncthreads();
    for (int i = tid; i < L; i += 256) colslab[(size_t)b * CAP + i] = (int)sorted[i];
}

// ---------- K4: layer-1 aggregation, one wave per dst; scalar col; bf16 h1 out ----------
__global__ __launch_bounds__(256) void agg1_kernel(
    const int* __restrict__ rowbeg, const int* __restrict__ rowend,
    const int* __restrict__ colslab,
    const float* __restrict__ s, const float* __restrict__ t,
    const unsigned short* __restrict__ hb, unsigned short* __restrict__ h1b) {
    int tid = threadIdx.x;
    int d = __builtin_amdgcn_readfirstlane(blockIdx.x * 4 + (tid >> 6));
    int lane = tid & 63, hh = lane >> 3;
    int beg = rowbeg[d], end = rowend[d];
    unsigned len = (unsigned)(end - beg);
    float tv = t[d * 8 + hh];
    float acc0 = 0.f, acc1 = 0.f, acc2 = 0.f, acc3 = 0.f;
    float den0 = 0.f, den1 = 0.f, den2 = 0.f, den3 = 0.f;
    for (int p = beg & ~3; p < end; p += 4) {
        int4 c4 = *(const int4*)(colslab + p);
        {
            bool ok = (unsigned)(p - beg) < len;
            int s0 = c4.x & 0x1FFFF; if (s0 >= N_NODES) s0 = 0;
            float e = __expf(lrelu(s[s0 * 8 + hh] + tv));
            e = ok ? e : 0.f;
            acc0 += e * bf2f(hb[(size_t)s0 * 64 + lane]); den0 += e;
        }
        {
            bool ok = (unsigned)(p + 1 - beg) < len;
            int s0 = c4.y & 0x1FFFF; if (s0 >= N_NODES) s0 = 0;
            float e = __expf(lrelu(s[s0 * 8 + hh] + tv));
            e = ok ? e : 0.f;
            acc1 += e * bf2f(hb[(size_t)s0 * 64 + lane]); den1 += e;
        }
        {
            bool ok = (unsigned)(p + 2 - beg) < len;
            int s0 = c4.z & 0x1FFFF; if (s0 >= N_NODES) s0 = 0;
            float e = __expf(lrelu(s[s0 * 8 + hh] + tv));
            e = ok ? e : 0.f;
            acc2 += e * bf2f(hb[(size_t)s0 * 64 + lane]); den2 += e;
        }
        {
            bool ok = (unsigned)(p + 3 - beg) < len;
            int s0 = c4.w & 0x1FFFF; if (s0 >= N_NODES) s0 = 0;
            float e = __expf(lrelu(s[s0 * 8 + hh] + tv));
            e = ok ? e : 0.f;
            acc3 += e * bf2f(hb[(size_t)s0 * 64 + lane]); den3 += e;
        }
    }
    float v = (acc0 + acc1 + acc2 + acc3) / (den0 + den1 + den2 + den3 + 1e-16f);
    float r = v > 0.f ? v : __expf(v) - 1.f;
    h1b[(size_t)d * 64 + lane] = (unsigned short)bf16rne(r);
}

// ---------- K5: h2 = h1@W2 (bf16 in/out); s2,t2 fused ----------
__global__ __launch_bounds__(256) void gemm2_kernel(
    const unsigned short* __restrict__ h1b, const float* __restrict__ W2,
    const float* __restrict__ a2s, const float* __restrict__ a2d,
    unsigned short* __restrict__ h2b, float* __restrict__ s2, float* __restrict__ t2) {
    __shared__ float Wl[64 * NC];       // 4 KB
    __shared__ float h1l[16 * 65];      // padded
    int tid = threadIdx.x;
    ((float4*)Wl)[tid] = ((const float4*)W2)[tid];
    {
        uint2 raw = ((const uint2*)h1b)[(size_t)blockIdx.x * 256 + tid];
        int f = tid * 4, rr = f >> 6, kk = f & 63;
        float* dp = &h1l[rr * 65 + kk];
        dp[0] = __uint_as_float(raw.x << 16);
        dp[1] = __uint_as_float(raw.x & 0xFFFF0000u);
        dp[2] = __uint_as_float(raw.y << 16);
        dp[3] = __uint_as_float(raw.y & 0xFFFF0000u);
    }
    __syncthreads();
    int c = tid & 15, r = tid >> 4;
    int n = blockIdx.x * 16 + r;
    float a = 0.f;
#pragma unroll 16
    for (int k = 0; k < 64; ++k) a += h1l[r * 65 + k] * Wl[k * NC + c];
    h2b[(size_t)n * NC + c] = (unsigned short)bf16rne(a);
    float vs = a * a2s[c];
    float vt = a * a2d[c];
#pragma unroll
    for (int o = 1; o < 16; o <<= 1) {
        vs += __shfl_xor(vs, o, 64);
        vt += __shfl_xor(vt, o, 64);
    }
    if (c == 0) { s2[n] = vs; t2[n] = vt; }
}

// ---------- K6: layer-2 aggregation + fused log_softmax, 16 lanes per dst ----------
__global__ __launch_bounds__(256) void agg2_kernel(
    const int* __restrict__ rowbeg, const int* __restrict__ rowend,
    const int* __restrict__ colslab,
    const float* __restrict__ s2, const float* __restrict__ t2,
    const unsigned short* __restrict__ h2b, float* __restrict__ out) {
    int tid = threadIdx.x;
    int d = blockIdx.x * 16 + (tid >> 4);
    int c = tid & 15;
    int beg = rowbeg[d], end = rowend[d];
    unsigned len = (unsigned)(end - beg);
    float tv = t2[d];
    float acc0 = 0.f, acc1 = 0.f, acc2 = 0.f, acc3 = 0.f;
    float den0 = 0.f, den1 = 0.f, den2 = 0.f, den3 = 0.f;
    for (int p = beg & ~3; p < end; p += 4) {
        int4 c4 = *(const int4*)(colslab + p);
        {
            bool ok = (unsigned)(p - beg) < len;
            int s0 = c4.x & 0x1FFFF; if (s0 >= N_NODES) s0 = 0;
            float e = __expf(lrelu(s2[s0] + tv));
            e = ok ? e : 0.f;
            acc0 += e * bf2f(h2b[(size_t)s0 * 16 + c]); den0 += e;
        }
        {
            bool ok = (unsigned)(p + 1 - beg) < len;
            int s0 = c4.y & 0x1FFFF; if (s0 >= N_NODES) s0 = 0;
            float e = __expf(lrelu(s2[s0] + tv));
            e = ok ? e : 0.f;
            acc1 += e * bf2f(h2b[(size_t)s0 * 16 + c]); den1 += e;
        }
        {
            bool ok = (unsigned)(p + 2 - beg) < len;
            int s0 = c4.z & 0x1FFFF; if (s0 >= N_NODES) s0 = 0;
            float e = __expf(lrelu(s2[s0] + tv));
            e = ok ? e : 0.f;
            acc2 += e * bf2f(h2b[(size_t)s0 * 16 + c]); den2 += e;
        }
        {
            bool ok = (unsigned)(p + 3 - beg) < len;
            int s0 = c4.w & 0x1FFFF; if (s0 >= N_NODES) s0 = 0;
            float e = __expf(lrelu(s2[s0] + tv));
            e = ok ? e : 0.f;
            acc3 += e * bf2f(h2b[(size_t)s0 * 16 + c]); den3 += e;
        }
    }
    float v = (acc0 + acc1 + acc2 + acc3) / (den0 + den1 + den2 + den3 + 1e-16f);
    float mx = v;
#pragma unroll
    for (int o = 1; o < 16; o <<= 1) mx = fmaxf(mx, __shfl_xor(mx, o, 64));
    float e = __expf(v - mx), sum = e;
#pragma unroll
    for (int o = 1; o < 16; o <<= 1) sum += __shfl_xor(sum, o, 64);
    out[(size_t)d * NC + c] = v - mx - __logf(sum);
}

extern "C" void kernel_launch(void* const* d_in, const int* in_sizes, int n_in,
                              void* d_out, int out_size, void* d_ws, size_t ws_size,
                              hipStream_t stream) {
    const float* x   = (const float*)d_in[0];
    const int*  eidx = (const int*)d_in[1];   // [2, E] int32
    const float* W1  = (const float*)d_in[2];
    const float* a1s = (const float*)d_in[3];
    const float* a1d = (const float*)d_in[4];
    const float* W2  = (const float*)d_in[5];
    const float* a2s = (const float*)d_in[6];
    const float* a2d = (const float*)d_in[7];
    float* out = (float*)d_out;
    const int* esrc = eidx;
    const int* edst = eidx + N_EDGES;

    // ---- workspace layout (all 16B-aligned) ----
    char* p = (char*)d_ws;
    int*      bcur    = (int*)p;      p += 512 * 4;                       // zeroed (2 KB)
    unsigned* tmp     = (unsigned*)p; p += (size_t)NBUCK * CAP * 4;       // 8.0 MB slabs
    int*      colslab = (int*)p;      p += (size_t)NBUCK * CAP * 4 + 64;  // 8.0 MB + pad
    int*      rowbeg  = (int*)p;      p += (size_t)N_NODES * 4;
    int*      rowend  = (int*)p;      p += (size_t)N_NODES * 4;
    float4*   Wt      = (float4*)p;   p += (size_t)2048 * 16;
    unsigned short* hb  = (unsigned short*)p; p += (size_t)N_NODES * 64 * 2;
    float*    s       = (float*)p;    p += (size_t)N_NODES * 8 * 4;
    float*    t       = (float*)p;    p += (size_t)N_NODES * 8 * 4;
    unsigned short* h1b = (unsigned short*)p; p += (size_t)N_NODES * 64 * 2;
    unsigned short* h2b = (unsigned short*)p; p += (size_t)N_NODES * NC * 2;
    float*    s2      = (float*)p;    p += (size_t)N_NODES * 4;
    float*    t2      = (float*)p;    p += (size_t)N_NODES * 4;

    hipMemsetAsync(bcur, 0, 512 * 4, stream);

    wtrans_kernel<<<8, 256, 0, stream>>>(W1, Wt);
    gemm1_kernel<<<(N_NODES + 127) / 128, 256, 0, stream>>>(x, Wt, a1s, a1d, hb, s, t);
    binscatter_kernel<<<NBLK2, 512, 0, stream>>>(esrc, edst, bcur, tmp);
    bsort_kernel<<<NBUCK, 256, 0, stream>>>(bcur, tmp, rowbeg, rowend, colslab);
    agg1_kernel<<<N_NODES / 4, 256, 0, stream>>>(rowbeg, rowend, colslab, s, t, hb, h1b);
    gemm2_kernel<<<N_NODES / 16, 256, 0, stream>>>(h1b, W2, a2s, a2d, h2b, s2, t2);
    agg2_kernel<<<N_NODES / 16, 256, 0, stream>>>(rowbeg, rowend, colslab, s2, t2, h2b, out);
}

// Round 7
// 342.856 us; speedup vs baseline: 3.6243x; 1.0129x over previous
//
#include <hip/hip_runtime.h>
#include <math.h>

#define N_NODES 100000
#define N_EDGES 1600000
#define NHEAD   8
#define NC      16
#define NEG     0.2f
#define BSH     8                 // 256 dst nodes per bucket
#define NBUCK   391               // ceil(100000/256)
#define CAP     5120              // slab capacity (mean 4092, sigma 64 -> +16 sigma)
#define TILE2   4096              // edges per binning block
#define NBLK2   391               // ceil(1600000/4096)

typedef __attribute__((ext_vector_type(4))) float f32x4;
typedef __attribute__((ext_vector_type(8))) short s16x8;

__device__ __forceinline__ float lrelu(float x) { return x > 0.f ? x : NEG * x; }
__device__ __forceinline__ short bf16rne(float f) {
    unsigned u = __float_as_uint(f);
    return (short)((u + 0x7FFFu + ((u >> 16) & 1u)) >> 16);
}
__device__ __forceinline__ float bf2f(unsigned short u) {
    return __uint_as_float(((unsigned)u) << 16);
}

// ---------- K0: pack W1 (256x64 f32) into bf16 fragment-major layout ----------
__global__ __launch_bounds__(256) void wtrans_kernel(const float* __restrict__ W1,
                                                     float4* __restrict__ Wt) {
    int u = blockIdx.x * 256 + threadIdx.x;   // 2048 units
    int j = u >> 9, ks = (u >> 6) & 7, l = u & 63;
    int colc = j * 16 + (l & 15);
    int k0 = ks * 32 + (l >> 4) * 8;
    union { s16x8 s; float4 f; } pk;
#pragma unroll
    for (int i = 0; i < 8; ++i) pk.s[i] = bf16rne(W1[(size_t)(k0 + i) * 64 + colc]);
    Wt[u] = pk.f;
}

// ---------- K1: h = x@W1 via bf16 MFMA; h->bf16; s,t fused from f32 acc ----------
__global__ __launch_bounds__(256) void gemm1_kernel(
    const float* __restrict__ x, const float4* __restrict__ Wt,
    const float* __restrict__ a1s, const float* __restrict__ a1d,
    unsigned short* __restrict__ hb, float* __restrict__ s, float* __restrict__ t) {
    __shared__ float4 WtL[2048];   // 32 KB, fragment-major
    int tid = threadIdx.x;
#pragma unroll
    for (int i = 0; i < 8; ++i) WtL[tid + i * 256] = Wt[tid + i * 256];
    int w = tid >> 6, lane = tid & 63;
    int n0 = blockIdx.x * 128;
    int r0 = n0 + w * 32 + (lane & 15);
    int r1 = r0 + 16;
    int cr0 = r0 < N_NODES ? r0 : 0;
    int cr1 = r1 < N_NODES ? r1 : 0;
    int koff = (lane >> 4) * 8;
    f32x4 acc[2][4];
#pragma unroll
    for (int r = 0; r < 2; ++r)
#pragma unroll
        for (int j = 0; j < 4; ++j) acc[r][j] = (f32x4)0.f;
    __syncthreads();
#pragma unroll
    for (int ks = 0; ks < 8; ++ks) {
        const float* p0 = x + (size_t)cr0 * 256 + ks * 32 + koff;
        const float* p1 = x + (size_t)cr1 * 256 + ks * 32 + koff;
        float4 a0l = *(const float4*)p0, a0h = *(const float4*)(p0 + 4);
        float4 a1l = *(const float4*)p1, a1h = *(const float4*)(p1 + 4);
        s16x8 A0, A1;
        A0[0] = bf16rne(a0l.x); A0[1] = bf16rne(a0l.y); A0[2] = bf16rne(a0l.z); A0[3] = bf16rne(a0l.w);
        A0[4] = bf16rne(a0h.x); A0[5] = bf16rne(a0h.y); A0[6] = bf16rne(a0h.z); A0[7] = bf16rne(a0h.w);
        A1[0] = bf16rne(a1l.x); A1[1] = bf16rne(a1l.y); A1[2] = bf16rne(a1l.z); A1[3] = bf16rne(a1l.w);
        A1[4] = bf16rne(a1h.x); A1[5] = bf16rne(a1h.y); A1[6] = bf16rne(a1h.z); A1[7] = bf16rne(a1h.w);
#pragma unroll
        for (int j = 0; j < 4; ++j) {
            s16x8 B = *(s16x8*)&WtL[(j * 8 + ks) * 64 + lane];
            acc[0][j] = __builtin_amdgcn_mfma_f32_16x16x32_bf16(A0, B, acc[0][j], 0, 0, 0);
            acc[1][j] = __builtin_amdgcn_mfma_f32_16x16x32_bf16(A1, B, acc[1][j], 0, 0, 0);
        }
    }
    // epilogue: D layout col=lane&15 + 16j, row=(lane>>4)*4+reg
    float asv[4], adv[4];
#pragma unroll
    for (int j = 0; j < 4; ++j) {
        int c = j * 16 + (lane & 15);
        asv[j] = a1s[c]; adv[j] = a1d[c];
    }
    int rbase = (lane >> 4) * 4;
#pragma unroll
    for (int r = 0; r < 2; ++r) {
#pragma unroll
        for (int reg = 0; reg < 4; ++reg) {
            int grow = n0 + w * 32 + r * 16 + rbase + reg;
            bool live = grow < N_NODES;
            unsigned short* hp = hb + (size_t)grow * 64 + (lane & 15);
#pragma unroll
            for (int j = 0; j < 4; ++j) {
                float hv = acc[r][j][reg];
                if (live) hp[j * 16] = (unsigned short)bf16rne(hv);
                float ps = hv * asv[j];
                float pt = hv * adv[j];
                ps += __shfl_xor(ps, 1, 64); ps += __shfl_xor(ps, 2, 64); ps += __shfl_xor(ps, 4, 64);
                pt += __shfl_xor(pt, 1, 64); pt += __shfl_xor(pt, 2, 64); pt += __shfl_xor(pt, 4, 64);
                if ((lane & 7) == 0 && live) {
                    int head = 2 * j + ((lane >> 3) & 1);
                    s[grow * 8 + head] = ps;
                    t[grow * 8 + head] = pt;
                }
            }
        }
    }
}

// ---------- K2: binned scatter into per-bucket slabs (wave-scan, 2 barriers) ----------
__global__ __launch_bounds__(512) void binscatter_kernel(
    const int* __restrict__ esrc, const int* __restrict__ edst,
    int* __restrict__ bcur, unsigned* __restrict__ tmp) {
    __shared__ unsigned buf[TILE2];              // 16 KB
    __shared__ int hist[512], lbase[512], cur[512], gbase[512], wsum[8];
    int tid = threadIdx.x;
    hist[tid] = 0; cur[tid] = 0;
    __syncthreads();
    int e0 = blockIdx.x * TILE2;
#pragma unroll
    for (int k = 0; k < TILE2 / 512; ++k) {
        int e = e0 + k * 512 + tid;
        if (e < N_EDGES) atomicAdd(&hist[edst[e] >> BSH], 1);
    }
    __syncthreads();
    int v = hist[tid];
    int w = tid >> 6, lane = tid & 63;
    int inc = v;
#pragma unroll
    for (int off = 1; off < 64; off <<= 1) {
        int nb = __shfl_up(inc, off, 64);
        if (lane >= off) inc += nb;
    }
    if (lane == 63) wsum[w] = inc;
    __syncthreads();
    int woff = 0;
    for (int k = 0; k < w; ++k) woff += wsum[k];
    lbase[tid] = inc - v + woff;
    gbase[tid] = v ? atomicAdd(&bcur[tid], v) : 0;
    __syncthreads();
#pragma unroll
    for (int k = 0; k < TILE2 / 512; ++k) {
        int e = e0 + k * 512 + tid;
        if (e < N_EDGES) {
            int d = edst[e];
            int b = d >> BSH;
            int p = lbase[b] + atomicAdd(&cur[b], 1);
            buf[p] = (unsigned)esrc[e] | ((unsigned)(d & ((1 << BSH) - 1)) << 17);
        }
    }
    __syncthreads();
    for (int b = w; b < 512; b += 8) {
        int L = hist[b];
        if (!L) continue;
        int lb = lbase[b];
        size_t base = (size_t)b * CAP + gbase[b];
        for (int i = lane; i < L; i += 64) tmp[base + i] = buf[lb + i];
    }
}

// ---------- K3: per-bucket LDS counting sort -> col slab + rowbeg/rowend ----------
__global__ __launch_bounds__(256) void bsort_kernel(
    const int* __restrict__ bcur, const unsigned* __restrict__ tmp,
    int* __restrict__ rowbeg, int* __restrict__ rowend, int* __restrict__ colslab) {
    __shared__ unsigned sorted[CAP];              // 20 KB
    __shared__ int cnt[256];
    __shared__ int wsum[4];
    int tid = threadIdx.x, b = blockIdx.x;
    int L = bcur[b];
    const unsigned* tb = tmp + (size_t)b * CAP;
    cnt[tid] = 0;
    __syncthreads();
    for (int i = tid; i < L; i += 256) atomicAdd(&cnt[tb[i] >> 17], 1);
    __syncthreads();
    int v = cnt[tid];
    int w = tid >> 6, lane = tid & 63;
    int inc = v;
#pragma unroll
    for (int off = 1; off < 64; off <<= 1) {
        int nb = __shfl_up(inc, off, 64);
        if (lane >= off) inc += nb;
    }
    if (lane == 63) wsum[w] = inc;
    __syncthreads();
    int woff = 0;
    for (int k = 0; k < w; ++k) woff += wsum[k];
    int ex = inc - v + woff;
    int node = (b << BSH) + tid;
    if (node < N_NODES) {
        rowbeg[node] = b * CAP + ex;
        rowend[node] = b * CAP + ex + v;
    }
    cnt[tid] = ex;                                // cursors
    __syncthreads();
    for (int i = tid; i < L; i += 256) {
        unsigned u = tb[i];
        int p = atomicAdd(&cnt[u >> 17], 1);
        sorted[p] = u & 0x1FFFFu;
    }
    __syncthreads();
    for (int i = tid; i < L; i += 256) colslab[(size_t)b * CAP + i] = (int)sorted[i];
}

// ---------- K4: layer-1 aggregation, wave/dst, shared-exp 8-edge batches ----------
__global__ __launch_bounds__(256) void agg1_kernel(
    const int* __restrict__ rowbeg, const int* __restrict__ rowend,
    const int* __restrict__ colslab,
    const float* __restrict__ s, const float* __restrict__ t,
    const unsigned short* __restrict__ hb, unsigned short* __restrict__ h1b) {
    int tid = threadIdx.x;
    int d = __builtin_amdgcn_readfirstlane(blockIdx.x * 4 + (tid >> 6));
    int lane = tid & 63;
    int hh = lane >> 3;           // head of this feature column (phase B)
    int hA = lane & 7;            // head this lane evaluates in phase A
    int sub = lane >> 3;          // edge-in-batch this lane evaluates in phase A
    int beg = rowbeg[d], end = rowend[d];
    float tvA = t[d * 8 + hA];
    float acc[4] = {0.f, 0.f, 0.f, 0.f};
    float den[4] = {0.f, 0.f, 0.f, 0.f};
    for (int p = beg; p < end; p += 8) {
        int pe = p + sub;
        int s0 = colslab[pe];                    // may be garbage past end
        if ((unsigned)s0 >= N_NODES) s0 = 0;
        float ev = __expf(lrelu(s[s0 * 8 + hA] + tvA));
        ev = (pe < end) ? ev : 0.f;
#pragma unroll
        for (int j = 0; j < 8; ++j) {
            float e = __shfl(ev, j * 8 + hh, 64);
            int sj  = __shfl(s0, j * 8, 64);     // uniform -> SGPR base
            acc[j & 3] += e * bf2f(hb[(size_t)sj * 64 + lane]);
            den[j & 3] += e;
        }
    }
    float v = (acc[0] + acc[1] + acc[2] + acc[3])
            / (den[0] + den[1] + den[2] + den[3] + 1e-16f);
    float r = v > 0.f ? v : __expf(v) - 1.f;
    h1b[(size_t)d * 64 + lane] = (unsigned short)bf16rne(r);
}

// ---------- K5: h2 = h1@W2 (bf16 in/out); s2,t2 fused ----------
__global__ __launch_bounds__(256) void gemm2_kernel(
    const unsigned short* __restrict__ h1b, const float* __restrict__ W2,
    const float* __restrict__ a2s, const float* __restrict__ a2d,
    unsigned short* __restrict__ h2b, float* __restrict__ s2, float* __restrict__ t2) {
    __shared__ float Wl[64 * NC];       // 4 KB
    __shared__ float h1l[16 * 65];      // padded
    int tid = threadIdx.x;
    ((float4*)Wl)[tid] = ((const float4*)W2)[tid];
    {
        uint2 raw = ((const uint2*)h1b)[(size_t)blockIdx.x * 256 + tid];
        int f = tid * 4, rr = f >> 6, kk = f & 63;
        float* dp = &h1l[rr * 65 + kk];
        dp[0] = __uint_as_float(raw.x << 16);
        dp[1] = __uint_as_float(raw.x & 0xFFFF0000u);
        dp[2] = __uint_as_float(raw.y << 16);
        dp[3] = __uint_as_float(raw.y & 0xFFFF0000u);
    }
    __syncthreads();
    int c = tid & 15, r = tid >> 4;
    int n = blockIdx.x * 16 + r;
    float a = 0.f;
#pragma unroll 16
    for (int k = 0; k < 64; ++k) a += h1l[r * 65 + k] * Wl[k * NC + c];
    h2b[(size_t)n * NC + c] = (unsigned short)bf16rne(a);
    float vs = a * a2s[c];
    float vt = a * a2d[c];
#pragma unroll
    for (int o = 1; o < 16; o <<= 1) {
        vs += __shfl_xor(vs, o, 64);
        vt += __shfl_xor(vt, o, 64);
    }
    if (c == 0) { s2[n] = vs; t2[n] = vt; }
}

// ---------- K6: layer-2 aggregation + log_softmax; shared-exp 16-edge batches ----------
__global__ __launch_bounds__(256) void agg2_kernel(
    const int* __restrict__ rowbeg, const int* __restrict__ rowend,
    const int* __restrict__ colslab,
    const float* __restrict__ s2, const float* __restrict__ t2,
    const unsigned short* __restrict__ h2b, float* __restrict__ out) {
    int tid = threadIdx.x;
    int d = blockIdx.x * 16 + (tid >> 4);
    int lane = tid & 63;
    int c = lane & 15;            // feature/class column
    int gb = lane & 48;           // 16-lane group base within wave
    int beg = rowbeg[d], end = rowend[d];
    float tv = t2[d];
    float acc[4] = {0.f, 0.f, 0.f, 0.f};
    float den[4] = {0.f, 0.f, 0.f, 0.f};
    for (int p = beg; p < end; p += 16) {
        int pe = p + c;                          // edge-in-batch = lane&15
        int s0 = colslab[pe];
        if ((unsigned)s0 >= N_NODES) s0 = 0;
        float ev = __expf(lrelu(s2[s0] + tv));
        ev = (pe < end) ? ev : 0.f;
#pragma unroll
        for (int j = 0; j < 16; ++j) {
            float e = __shfl(ev, gb + j, 64);
            int sj  = __shfl(s0, gb + j, 64);
            acc[j & 3] += e * bf2f(h2b[(size_t)sj * 16 + c]);
            den[j & 3] += e;
        }
    }
    float v = (acc[0] + acc[1] + acc[2] + acc[3])
            / (den[0] + den[1] + den[2] + den[3] + 1e-16f);
    float mx = v;
#pragma unroll
    for (int o = 1; o < 16; o <<= 1) mx = fmaxf(mx, __shfl_xor(mx, o, 64));
    float e = __expf(v - mx), sum = e;
#pragma unroll
    for (int o = 1; o < 16; o <<= 1) sum += __shfl_xor(sum, o, 64);
    out[(size_t)d * NC + c] = v - mx - __logf(sum);
}

extern "C" void kernel_launch(void* const* d_in, const int* in_sizes, int n_in,
                              void* d_out, int out_size, void* d_ws, size_t ws_size,
                              hipStream_t stream) {
    const float* x   = (const float*)d_in[0];
    const int*  eidx = (const int*)d_in[1];   // [2, E] int32
    const float* W1  = (const float*)d_in[2];
    const float* a1s = (const float*)d_in[3];
    const float* a1d = (const float*)d_in[4];
    const float* W2  = (const float*)d_in[5];
    const float* a2s = (const float*)d_in[6];
    const float* a2d = (const float*)d_in[7];
    float* out = (float*)d_out;
    const int* esrc = eidx;
    const int* edst = eidx + N_EDGES;

    // ---- workspace layout (all 16B-aligned) ----
    char* p = (char*)d_ws;
    int*      bcur    = (int*)p;      p += 512 * 4;                       // zeroed (2 KB)
    unsigned* tmp     = (unsigned*)p; p += (size_t)NBUCK * CAP * 4;       // 8.0 MB slabs
    int*      colslab = (int*)p;      p += (size_t)NBUCK * CAP * 4 + 64;  // 8.0 MB + pad
    int*      rowbeg  = (int*)p;      p += (size_t)N_NODES * 4;
    int*      rowend  = (int*)p;      p += (size_t)N_NODES * 4;
    float4*   Wt      = (float4*)p;   p += (size_t)2048 * 16;
    unsigned short* hb  = (unsigned short*)p; p += (size_t)N_NODES * 64 * 2;
    float*    s       = (float*)p;    p += (size_t)N_NODES * 8 * 4;
    float*    t       = (float*)p;    p += (size_t)N_NODES * 8 * 4;
    unsigned short* h1b = (unsigned short*)p; p += (size_t)N_NODES * 64 * 2;
    unsigned short* h2b = (unsigned short*)p; p += (size_t)N_NODES * NC * 2;
    float*    s2      = (float*)p;    p += (size_t)N_NODES * 4;
    float*    t2      = (float*)p;    p += (size_t)N_NODES * 4;

    hipMemsetAsync(bcur, 0, 512 * 4, stream);

    wtrans_kernel<<<8, 256, 0, stream>>>(W1, Wt);
    gemm1_kernel<<<(N_NODES + 127) / 128, 256, 0, stream>>>(x, Wt, a1s, a1d, hb, s, t);
    binscatter_kernel<<<NBLK2, 512, 0, stream>>>(esrc, edst, bcur, tmp);
    bsort_kernel<<<NBUCK, 256, 0, stream>>>(bcur, tmp, rowbeg, rowend, colslab);
    agg1_kernel<<<N_NODES / 4, 256, 0, stream>>>(rowbeg, rowend, colslab, s, t, hb, h1b);
    gemm2_kernel<<<N_NODES / 16, 256, 0, stream>>>(h1b, W2, a2s, a2d, h2b, s2, t2);
    agg2_kernel<<<N_NODES / 16, 256, 0, stream>>>(rowbeg, rowend, colslab, s2, t2, h2b, out);
}